// Round 1
// baseline (980.644 us; speedup 1.0000x reference)
//
#include <hip/hip_runtime.h>
#include <math.h>

#define D_MODEL 1024
#define SEQ     2048
#define NBATCH  2
#define NTOK    (NBATCH * SEQ)
#define NH      16
#define HD      64

// ---------------- mask dtype detect / convert ----------------
// padding_mask is bool in the reference; harness may hand us uint8 / int32 /
// float32. Detect from byte patterns (90% of values are nonzero):
//   uint8:  bytes at i%4==1 are mostly nonzero
//   float32: bytes at i%4==3 are mostly 0x3f (1.0f), i%4==1 all zero
//   int32:  only i%4==0 bytes nonzero
__global__ void mask_detect_kernel(const unsigned char* __restrict__ m,
                                   int* __restrict__ flag) {
  __shared__ int c1s, c3s;
  if (threadIdx.x == 0) { c1s = 0; c3s = 0; }
  __syncthreads();
  int c1 = 0, c3 = 0;
  for (int i = threadIdx.x; i < NTOK; i += 256) {  // first 4096 bytes: safe for all 3 dtypes
    unsigned char v = m[i];
    if (v) {
      if ((i & 3) == 1) c1++;
      if ((i & 3) == 3) c3++;
    }
  }
  if (c1) atomicAdd(&c1s, c1);
  if (c3) atomicAdd(&c3s, c3);
  __syncthreads();
  if (threadIdx.x == 0) *flag = (c1s > 0) ? 1 : ((c3s > 0) ? 2 : 0);
}

__global__ void mask_convert_kernel(const void* __restrict__ m,
                                    const int* __restrict__ flag,
                                    float* __restrict__ maskAdd) {
  int i = blockIdx.x * 256 + threadIdx.x;
  if (i >= NTOK) return;
  int f = *flag;
  bool on;
  if (f == 1)      on = ((const unsigned char*)m)[i] != 0;
  else if (f == 2) on = ((const float*)m)[i] != 0.0f;
  else             on = ((const int*)m)[i] != 0;
  maskAdd[i] = on ? 0.0f : -1e30f;
}

// ---------------- LayerNorm (one block per token row of 1024) ----------------
__device__ inline float block_reduce_sum(float v, float* red) {
  #pragma unroll
  for (int s = 1; s < 64; s <<= 1) v += __shfl_xor(v, s);
  int wid = threadIdx.x >> 6, lane = threadIdx.x & 63;
  if (lane == 0) red[wid] = v;
  __syncthreads();
  float t = red[0] + red[1] + red[2] + red[3];
  __syncthreads();
  return t;
}

__global__ __launch_bounds__(256) void ln_kernel(const float* __restrict__ x,
                                                 const float* __restrict__ w,
                                                 const float* __restrict__ b,
                                                 float* __restrict__ y) {
  __shared__ float red[4];
  int row = blockIdx.x;
  int tid = threadIdx.x;
  float4 v = ((const float4*)(x + (size_t)row * D_MODEL))[tid];
  float s = v.x + v.y + v.z + v.w;
  float tot = block_reduce_sum(s, red);
  float mu = tot * (1.0f / D_MODEL);
  float dx = v.x - mu, dy = v.y - mu, dz = v.z - mu, dw = v.w - mu;
  float sq = dx * dx + dy * dy + dz * dz + dw * dw;
  float tot2 = block_reduce_sum(sq, red);
  float inv = rsqrtf(tot2 * (1.0f / D_MODEL) + 1e-5f);
  float4 wv = ((const float4*)w)[tid];
  float4 bv = ((const float4*)b)[tid];
  float4 o;
  o.x = dx * inv * wv.x + bv.x;
  o.y = dy * inv * wv.y + bv.y;
  o.z = dz * inv * wv.z + bv.z;
  o.w = dw * inv * wv.w + bv.w;
  ((float4*)(y + (size_t)row * D_MODEL))[tid] = o;
}

// ---------------- generic fp32 GEMM: C = A(MxK) * B(KxN) + bias ----------------
#define BM 128
#define BN 128
#define BK 16

__global__ __launch_bounds__(256) void gemm_bias_kernel(
    const float* __restrict__ A, const float* __restrict__ B,
    const float* __restrict__ bias, float* __restrict__ C,
    int M, int N, int K) {
  __shared__ float As[BK][BM + 4];  // [k][m]; row stride 132 fl = 528B (16B aligned)
  __shared__ float Bs[BK][BN + 4];  // [k][n]
  int tid = threadIdx.x;
  int tx = tid & 15, ty = tid >> 4;
  int m0 = blockIdx.y * BM, n0 = blockIdx.x * BN;
  float acc[8][8] = {};
  for (int k0 = 0; k0 < K; k0 += BK) {
    // A tile 128x16: 512 float4 along K
    #pragma unroll
    for (int i = 0; i < 2; i++) {
      int f = tid + 256 * i;
      int r = f >> 2;
      int kc = (f & 3) << 2;
      float4 a = *(const float4*)(A + (size_t)(m0 + r) * K + k0 + kc);
      As[kc + 0][r] = a.x;
      As[kc + 1][r] = a.y;
      As[kc + 2][r] = a.z;
      As[kc + 3][r] = a.w;
    }
    // B tile 16x128: 512 float4 along N
    #pragma unroll
    for (int i = 0; i < 2; i++) {
      int f = tid + 256 * i;
      int kk = f >> 5;
      int c = (f & 31) << 2;
      *(float4*)&Bs[kk][c] = *(const float4*)(B + (size_t)(k0 + kk) * N + n0 + c);
    }
    __syncthreads();
    #pragma unroll
    for (int kk = 0; kk < BK; kk++) {
      float a8[8], b8[8];
      *(float4*)&a8[0] = *(const float4*)&As[kk][ty * 8];
      *(float4*)&a8[4] = *(const float4*)&As[kk][ty * 8 + 4];
      *(float4*)&b8[0] = *(const float4*)&Bs[kk][tx * 8];
      *(float4*)&b8[4] = *(const float4*)&Bs[kk][tx * 8 + 4];
      #pragma unroll
      for (int i = 0; i < 8; i++)
        #pragma unroll
        for (int j = 0; j < 8; j++)
          acc[i][j] = fmaf(a8[i], b8[j], acc[i][j]);
    }
    __syncthreads();
  }
  #pragma unroll
  for (int i = 0; i < 8; i++) {
    int r = m0 + ty * 8 + i;
    #pragma unroll
    for (int j = 0; j < 8; j += 4) {
      int c = n0 + tx * 8 + j;
      float4 o;
      o.x = acc[i][j + 0] + bias[c + 0];
      o.y = acc[i][j + 1] + bias[c + 1];
      o.z = acc[i][j + 2] + bias[c + 2];
      o.w = acc[i][j + 3] + bias[c + 3];
      *(float4*)(C + (size_t)r * N + c) = o;
    }
  }
}

// ---------------- flash attention (fp32) ----------------
// grid: (SEQ/64, NH, NBATCH), block 256 (16x16 threads, 4x4 outputs each)
// qkv layout: [tok][3][NH][HD] flat = tok*3072 + which*1024 + h*64 + d
__global__ __launch_bounds__(256) void attn_kernel(
    const float* __restrict__ qkv, const float* __restrict__ maskAddG,
    float* __restrict__ av) {
  __shared__ float Qt[HD][72];    // [d][r^swz]
  __shared__ float KtPs[HD][72];  // Kt: [d][c^swz]; reused as Ps[r][kk] after barrier
  __shared__ float Vs[64][72];    // [kk][d]
  __shared__ float mAdd[64];
  int tid = threadIdx.x;
  int tx = tid & 15, ty = tid >> 4;
  int qt = blockIdx.x, bh = blockIdx.y, bn = blockIdx.z;
  size_t tokBase = (size_t)bn * SEQ;
  const float* qbase = qkv + (tokBase + qt * 64) * 3072 + bh * HD;

  // stage Q (pre-scaled by 1/sqrt(hd)), d-major with column swizzle
  #pragma unroll
  for (int i = 0; i < 4; i++) {
    int f = tid + 256 * i;          // 0..1023
    int r = f >> 4;                 // 0..63
    int dc = (f & 15) << 2;         // 0..60
    float4 q = *(const float4*)(qbase + (size_t)r * 3072 + dc);
    int rc = r ^ (((dc >> 2) & 3) << 2);
    Qt[dc + 0][rc] = q.x * 0.125f;
    Qt[dc + 1][rc] = q.y * 0.125f;
    Qt[dc + 2][rc] = q.z * 0.125f;
    Qt[dc + 3][rc] = q.w * 0.125f;
  }

  float m[4], l[4], o[4][4];
  #pragma unroll
  for (int i = 0; i < 4; i++) {
    m[i] = -1e38f; l[i] = 0.0f;
    #pragma unroll
    for (int j = 0; j < 4; j++) o[i][j] = 0.0f;
  }

  for (int kt = 0; kt < SEQ / 64; kt++) {
    const float* kbase = qkv + (tokBase + kt * 64) * 3072 + 1024 + bh * HD;
    const float* vbase = kbase + 1024;
    __syncthreads();  // prior tile's Ps/Vs reads done (also covers Q staging, iter 0)
    #pragma unroll
    for (int i = 0; i < 4; i++) {
      int f = tid + 256 * i;
      int c = f >> 4;
      int dc = (f & 15) << 2;
      float4 kq = *(const float4*)(kbase + (size_t)c * 3072 + dc);
      int cc = c ^ (((dc >> 2) & 3) << 2);
      KtPs[dc + 0][cc] = kq.x;
      KtPs[dc + 1][cc] = kq.y;
      KtPs[dc + 2][cc] = kq.z;
      KtPs[dc + 3][cc] = kq.w;
      *(float4*)&Vs[c][dc] = *(const float4*)(vbase + (size_t)c * 3072 + dc);
    }
    if (tid < 64) mAdd[tid] = maskAddG[tokBase + kt * 64 + tid];
    __syncthreads();

    // S = (Q/8) K^T, 4x4 per thread
    float s[4][4] = {};
    #pragma unroll 8
    for (int d = 0; d < 64; d++) {
      int sw = ((d >> 2) & 3) << 2;
      float4 q4 = *(const float4*)&Qt[d][(4 * ty) ^ sw];
      float4 k4 = *(const float4*)&KtPs[d][(4 * tx) ^ sw];
      float qv[4] = {q4.x, q4.y, q4.z, q4.w};
      float kv[4] = {k4.x, k4.y, k4.z, k4.w};
      #pragma unroll
      for (int i = 0; i < 4; i++)
        #pragma unroll
        for (int j = 0; j < 4; j++)
          s[i][j] = fmaf(qv[i], kv[j], s[i][j]);
    }
    float ma[4] = {mAdd[4 * tx + 0], mAdd[4 * tx + 1], mAdd[4 * tx + 2], mAdd[4 * tx + 3]};

    // online softmax update (rows owned by ty-group; reduce across 16 tx lanes)
    #pragma unroll
    for (int i = 0; i < 4; i++) {
      #pragma unroll
      for (int j = 0; j < 4; j++) s[i][j] += ma[j];
      float rm = fmaxf(fmaxf(s[i][0], s[i][1]), fmaxf(s[i][2], s[i][3]));
      rm = fmaxf(rm, __shfl_xor(rm, 1));
      rm = fmaxf(rm, __shfl_xor(rm, 2));
      rm = fmaxf(rm, __shfl_xor(rm, 4));
      rm = fmaxf(rm, __shfl_xor(rm, 8));
      float mn = fmaxf(m[i], rm);
      float alpha = __expf(m[i] - mn);
      float rs = 0.0f;
      #pragma unroll
      for (int j = 0; j < 4; j++) {
        float p = __expf(s[i][j] - mn);
        s[i][j] = p;
        rs += p;
      }
      rs += __shfl_xor(rs, 1);
      rs += __shfl_xor(rs, 2);
      rs += __shfl_xor(rs, 4);
      rs += __shfl_xor(rs, 8);
      l[i] = l[i] * alpha + rs;
      m[i] = mn;
      #pragma unroll
      for (int j = 0; j < 4; j++) o[i][j] *= alpha;
    }

    __syncthreads();  // everyone done reading Kt before overwriting as Ps
    #pragma unroll
    for (int i = 0; i < 4; i++) {
      float4 p4 = {s[i][0], s[i][1], s[i][2], s[i][3]};
      *(float4*)&KtPs[4 * ty + i][4 * tx] = p4;
    }
    __syncthreads();

    // O += P * V
    #pragma unroll 4
    for (int kg = 0; kg < 16; kg++) {
      float p_[4][4];
      #pragma unroll
      for (int i = 0; i < 4; i++) {
        float4 t = *(const float4*)&KtPs[4 * ty + i][4 * kg];
        p_[i][0] = t.x; p_[i][1] = t.y; p_[i][2] = t.z; p_[i][3] = t.w;
      }
      #pragma unroll
      for (int u = 0; u < 4; u++) {
        float4 v4 = *(const float4*)&Vs[4 * kg + u][4 * tx];
        float vv[4] = {v4.x, v4.y, v4.z, v4.w};
        #pragma unroll
        for (int i = 0; i < 4; i++)
          #pragma unroll
          for (int j = 0; j < 4; j++)
            o[i][j] = fmaf(p_[i][u], vv[j], o[i][j]);
      }
    }
  }

  // epilogue: O / l -> attn_vec[tok][bh*64 + c]
  float* outp = av + (tokBase + qt * 64) * D_MODEL + bh * HD;
  #pragma unroll
  for (int i = 0; i < 4; i++) {
    float invl = 1.0f / l[i];
    float4 o4 = {o[i][0] * invl, o[i][1] * invl, o[i][2] * invl, o[i][3] * invl};
    *(float4*)(outp + (size_t)(4 * ty + i) * D_MODEL + 4 * tx) = o4;
  }
}

// ---------------- launch ----------------
extern "C" void kernel_launch(void* const* d_in, const int* in_sizes, int n_in,
                              void* d_out, int out_size, void* d_ws, size_t ws_size,
                              hipStream_t stream) {
  const float* x        = (const float*)d_in[0];
  const void*  mask     = d_in[1];
  const float* ln_in_w  = (const float*)d_in[2];
  const float* ln_in_b  = (const float*)d_in[3];
  const float* qkv_w    = (const float*)d_in[4];
  const float* qkv_b    = (const float*)d_in[5];
  const float* out_w    = (const float*)d_in[6];
  const float* out_b    = (const float*)d_in[7];
  const float* ln_out_w = (const float*)d_in[8];
  const float* ln_out_b = (const float*)d_in[9];
  float* out = (float*)d_out;

  char* ws = (char*)d_ws;
  float* xn      = (float*)(ws);                                // 16 MB, reused as proj
  float* qkv     = (float*)(ws + (size_t)16 * 1024 * 1024);     // 48 MB
  float* av      = (float*)(ws + (size_t)64 * 1024 * 1024);     // 16 MB
  float* proj    = xn;                                          // alias (xn dead after GEMM1)
  float* maskAdd = (float*)(ws + (size_t)80 * 1024 * 1024);     // 16 KB
  int*   flag    = (int*)(ws + (size_t)80 * 1024 * 1024 + 16384);

  mask_detect_kernel<<<1, 256, 0, stream>>>((const unsigned char*)mask, flag);
  mask_convert_kernel<<<(NTOK + 255) / 256, 256, 0, stream>>>(mask, flag, maskAdd);
  ln_kernel<<<NTOK, 256, 0, stream>>>(x, ln_in_w, ln_in_b, xn);
  gemm_bias_kernel<<<dim3(3 * D_MODEL / BN, NTOK / BM), 256, 0, stream>>>(
      xn, qkv_w, qkv_b, qkv, NTOK, 3 * D_MODEL, D_MODEL);
  attn_kernel<<<dim3(SEQ / 64, NH, NBATCH), 256, 0, stream>>>(qkv, maskAdd, av);
  gemm_bias_kernel<<<dim3(D_MODEL / BN, NTOK / BM), 256, 0, stream>>>(
      av, out_w, out_b, proj, NTOK, D_MODEL, D_MODEL);
  ln_kernel<<<NTOK, 256, 0, stream>>>(proj, ln_out_w, ln_out_b, out);
}

// Round 3
// 225.431 us; speedup vs baseline: 4.3501x; 4.3501x over previous
//
#include <hip/hip_runtime.h>
#include <math.h>

#define D_MODEL 1024
#define SEQ     2048
#define NBATCH  2
#define NTOK    (NBATCH * SEQ)
#define NH      16
#define HD      64

typedef float f32x4 __attribute__((ext_vector_type(4)));
typedef short bf16x8 __attribute__((ext_vector_type(8)));

__device__ __forceinline__ unsigned short f2bf(float f) {
  unsigned u = __builtin_bit_cast(unsigned, f);
  u += 0x7FFFu + ((u >> 16) & 1u);
  return (unsigned short)(u >> 16);
}

__device__ __forceinline__ void gload16(const void* g, void* l) {
  __builtin_amdgcn_global_load_lds(
      (const __attribute__((address_space(1))) void*)g,
      (__attribute__((address_space(3))) void*)l, 16, 0, 0);
}

// ---------------- mask dtype detect / convert (unchanged, verified) ----------------
__global__ void mask_detect_kernel(const unsigned char* __restrict__ m,
                                   int* __restrict__ flag) {
  __shared__ int c1s, c3s;
  if (threadIdx.x == 0) { c1s = 0; c3s = 0; }
  __syncthreads();
  int c1 = 0, c3 = 0;
  for (int i = threadIdx.x; i < NTOK; i += 256) {
    unsigned char v = m[i];
    if (v) {
      if ((i & 3) == 1) c1++;
      if ((i & 3) == 3) c3++;
    }
  }
  if (c1) atomicAdd(&c1s, c1);
  if (c3) atomicAdd(&c3s, c3);
  __syncthreads();
  if (threadIdx.x == 0) *flag = (c1s > 0) ? 1 : ((c3s > 0) ? 2 : 0);
}

__global__ void mask_convert_kernel(const void* __restrict__ m,
                                    const int* __restrict__ flag,
                                    float* __restrict__ maskAdd) {
  int i = blockIdx.x * 256 + threadIdx.x;
  if (i >= NTOK) return;
  int f = *flag;
  bool on;
  if (f == 1)      on = ((const unsigned char*)m)[i] != 0;
  else if (f == 2) on = ((const float*)m)[i] != 0.0f;
  else             on = ((const int*)m)[i] != 0;
  maskAdd[i] = on ? 0.0f : -1e30f;
}

// ---------------- LayerNorm (templated output dtype) ----------------
__device__ inline float block_reduce_sum(float v, float* red) {
  #pragma unroll
  for (int s = 1; s < 64; s <<= 1) v += __shfl_xor(v, s);
  int wid = threadIdx.x >> 6, lane = threadIdx.x & 63;
  if (lane == 0) red[wid] = v;
  __syncthreads();
  float t = red[0] + red[1] + red[2] + red[3];
  __syncthreads();
  return t;
}

template <bool BF16OUT>
__global__ __launch_bounds__(256) void ln_kernel(const float* __restrict__ x,
                                                 const float* __restrict__ w,
                                                 const float* __restrict__ b,
                                                 void* __restrict__ yv) {
  __shared__ float red[4];
  int row = blockIdx.x;
  int tid = threadIdx.x;
  float4 v = ((const float4*)(x + (size_t)row * D_MODEL))[tid];
  float s = v.x + v.y + v.z + v.w;
  float tot = block_reduce_sum(s, red);
  float mu = tot * (1.0f / D_MODEL);
  float dx = v.x - mu, dy = v.y - mu, dz = v.z - mu, dw = v.w - mu;
  float sq = dx * dx + dy * dy + dz * dz + dw * dw;
  float tot2 = block_reduce_sum(sq, red);
  float inv = rsqrtf(tot2 * (1.0f / D_MODEL) + 1e-5f);
  float4 wv = ((const float4*)w)[tid];
  float4 bv = ((const float4*)b)[tid];
  float4 o;
  o.x = dx * inv * wv.x + bv.x;
  o.y = dy * inv * wv.y + bv.y;
  o.z = dz * inv * wv.z + bv.z;
  o.w = dw * inv * wv.w + bv.w;
  if constexpr (BF16OUT) {
    ushort4 o4 = {f2bf(o.x), f2bf(o.y), f2bf(o.z), f2bf(o.w)};
    ((ushort4*)((unsigned short*)yv + (size_t)row * D_MODEL))[tid] = o4;
  } else {
    ((float4*)((float*)yv + (size_t)row * D_MODEL))[tid] = o;
  }
}

// ---------------- weight transpose+convert: W[K][N] f32 -> WT[N][K] bf16 ----------------
__global__ __launch_bounds__(256) void transpose_convert_kernel(
    const float* __restrict__ W, unsigned short* __restrict__ WT, int K, int N) {
  __shared__ float t[64][65];
  int k0 = blockIdx.y * 64, n0 = blockIdx.x * 64;
  int tid = threadIdx.x;
  int rr = tid >> 4, cc = (tid & 15) * 4;
  #pragma unroll
  for (int i = 0; i < 4; i++) {
    int rk = i * 16 + rr;
    float4 v = *(const float4*)&W[(size_t)(k0 + rk) * N + n0 + cc];
    t[rk][cc + 0] = v.x; t[rk][cc + 1] = v.y; t[rk][cc + 2] = v.z; t[rk][cc + 3] = v.w;
  }
  __syncthreads();
  #pragma unroll
  for (int i = 0; i < 4; i++) {
    int rn = i * 16 + rr;
    ushort4 o = {f2bf(t[cc + 0][rn]), f2bf(t[cc + 1][rn]),
                 f2bf(t[cc + 2][rn]), f2bf(t[cc + 3][rn])};
    *(ushort4*)&WT[(size_t)(n0 + rn) * K + k0 + cc] = o;
  }
}

// ---------------- V transpose: qkv[tok][2048+h*64+d] bf16 -> Vt[(n*16+h)*64+d][s] ----------------
__global__ __launch_bounds__(256) void v_transpose_kernel(
    const unsigned short* __restrict__ qkv, unsigned short* __restrict__ Vt) {
  __shared__ unsigned short t[64][66];
  int s0 = blockIdx.x * 64;
  int h = blockIdx.y, n = blockIdx.z;
  int tid = threadIdx.x;
  #pragma unroll
  for (int i = 0; i < 2; i++) {
    int ch = i * 256 + tid;
    int sr = ch >> 3, c8 = (ch & 7) * 8;
    const unsigned short* src =
        qkv + (size_t)(n * SEQ + s0 + sr) * 3072 + 2048 + h * 64 + c8;
    uint4 v = *(const uint4*)src;
    unsigned short tmp[8];
    *(uint4*)tmp = v;
    #pragma unroll
    for (int j = 0; j < 8; j++) t[sr][c8 + j] = tmp[j];
  }
  __syncthreads();
  #pragma unroll
  for (int i = 0; i < 2; i++) {
    int ch = i * 256 + tid;
    int d = ch >> 3, s8 = (ch & 7) * 8;
    unsigned short tmp[8];
    #pragma unroll
    for (int j = 0; j < 8; j++) tmp[j] = t[s8 + j][d];
    unsigned short* dst =
        Vt + ((size_t)((n * NH + h) * HD) + d) * SEQ + s0 + s8;
    *(uint4*)dst = *(const uint4*)tmp;
  }
}

// ---------------- bf16 MFMA GEMM: C = A(MxK) * B(KxN) + bias, B given as BT[N][K] ----------------
// 128x128 tile, BK=64, 4 waves (2x2), wave tile 64x64 = 4x4 MFMA 16x16x32 tiles.
// LDS linear chunks + pre-swizzled global source: LDS[row][cb] = global[row][cb^(row&7)].
template <typename OutT>
__global__ __launch_bounds__(256) void gemm_mfma_kernel(
    const unsigned short* __restrict__ A, const unsigned short* __restrict__ BT,
    const float* __restrict__ bias, OutT* __restrict__ C, int M, int N, int K) {
  __shared__ __align__(16) char As[16384];
  __shared__ __align__(16) char Bs[16384];
  int tid = threadIdx.x;
  int lane = tid & 63, w = tid >> 6;
  int r = lane & 15, g = lane >> 4;
  int wm = w >> 1, wn = w & 1;
  int m0 = blockIdx.y * 128, n0 = blockIdx.x * 128;
  f32x4 acc[4][4] = {};

  const char* Ab = (const char*)A;
  const char* Bb = (const char*)BT;
  for (int k0 = 0; k0 < K; k0 += 64) {
    __syncthreads();
    #pragma unroll
    for (int i = 0; i < 4; i++) {
      int chb = i * 256 + w * 64;
      int ch = chb + lane;
      int row = ch >> 3, cb = (ch & 7) ^ (row & 7);
      gload16(Ab + (((size_t)(m0 + row) * K + k0) << 1) + (cb << 4), As + chb * 16);
      gload16(Bb + (((size_t)(n0 + row) * K + k0) << 1) + (cb << 4), Bs + chb * 16);
    }
    __syncthreads();
    #pragma unroll
    for (int s = 0; s < 2; s++) {
      bf16x8 af[4], bfr[4];
      #pragma unroll
      for (int mt = 0; mt < 4; mt++) {
        int arow = wm * 64 + mt * 16 + r;
        int cb = (s * 4 + g) ^ (arow & 7);
        af[mt] = *(const bf16x8*)(As + arow * 128 + cb * 16);
      }
      #pragma unroll
      for (int nt = 0; nt < 4; nt++) {
        int brow = wn * 64 + nt * 16 + r;
        int cb = (s * 4 + g) ^ (brow & 7);
        bfr[nt] = *(const bf16x8*)(Bs + brow * 128 + cb * 16);
      }
      #pragma unroll
      for (int mt = 0; mt < 4; mt++)
        #pragma unroll
        for (int nt = 0; nt < 4; nt++)
          acc[mt][nt] = __builtin_amdgcn_mfma_f32_16x16x32_bf16(
              af[mt], bfr[nt], acc[mt][nt], 0, 0, 0);
    }
  }
  #pragma unroll
  for (int nt = 0; nt < 4; nt++) {
    int col = n0 + wn * 64 + nt * 16 + r;
    float bv = bias[col];
    #pragma unroll
    for (int mt = 0; mt < 4; mt++) {
      #pragma unroll
      for (int rr = 0; rr < 4; rr++) {
        int row = m0 + wm * 64 + mt * 16 + g * 4 + rr;
        float v = acc[mt][nt][rr] + bv;
        if constexpr (sizeof(OutT) == 2) {
          C[(size_t)row * N + col] = (OutT)f2bf(v);
        } else {
          C[(size_t)row * N + col] = v;
        }
      }
    }
  }
}

// ---------------- MFMA flash attention ----------------
// grid (SEQ/128, NH, NBATCH), 256 thr = 4 waves; wave w owns q-rows [w*32, w*32+32).
__global__ __launch_bounds__(256) void attn_mfma_kernel(
    const unsigned short* __restrict__ qkv, const unsigned short* __restrict__ Vt,
    const float* __restrict__ maskAddG, unsigned short* __restrict__ av) {
  __shared__ __align__(16) char Q_s[16384];  // [qrow 128][d 64] bf16, chunk-swizzled
  __shared__ __align__(16) char K_s[8192];   // [kv 64][d 64]
  __shared__ __align__(16) char V_s[8192];   // [d 64][kv 64]  (V^T)
  __shared__ __align__(16) char P_s[16384];  // per-wave [qrow 32][kv 64]
  int tid = threadIdx.x;
  int lane = tid & 63, w = tid >> 6;
  int r = lane & 15, g = lane >> 4;
  int qt = blockIdx.x, h = blockIdx.y, bn = blockIdx.z;
  size_t tok0 = (size_t)bn * SEQ;

  const char* qb = (const char*)qkv + (((tok0 + qt * 128) * 3072) + h * 64) * 2;
  #pragma unroll
  for (int i = 0; i < 4; i++) {
    int chb = i * 256 + w * 64;
    int ch = chb + lane;
    int row = ch >> 3, cb = (ch & 7) ^ (row & 7);
    gload16(qb + (size_t)row * 6144 + (cb << 4), Q_s + chb * 16);
  }

  float mstate[2][4], lstate[2][4];
  f32x4 o_acc[2][4] = {};
  #pragma unroll
  for (int mt = 0; mt < 2; mt++)
    #pragma unroll
    for (int rr = 0; rr < 4; rr++) { mstate[mt][rr] = -INFINITY; lstate[mt][rr] = 0.f; }

  char* Pw = P_s + w * 4096;

  for (int kt = 0; kt < SEQ / 64; kt++) {
    __syncthreads();  // all waves done reading K_s/V_s from previous tile
    const char* kb = (const char*)qkv + (((tok0 + kt * 64) * 3072) + 1024 + h * 64) * 2;
    const char* vb = (const char*)Vt + ((((size_t)(bn * NH + h) * HD) * SEQ) + kt * 64) * 2;
    #pragma unroll
    for (int i = 0; i < 2; i++) {
      int chb = i * 256 + w * 64;
      int ch = chb + lane;
      int row = ch >> 3, cb = (ch & 7) ^ (row & 7);
      gload16(kb + (size_t)row * 6144 + (cb << 4), K_s + chb * 16);
      gload16(vb + (size_t)row * 4096 + (cb << 4), V_s + chb * 16);
    }
    __syncthreads();  // staging complete (vmcnt drained at barrier)

    // ---- S = Q K^T  (A=Q, B=K^T; both read along d) ----
    f32x4 sa[2][4] = {};
    #pragma unroll
    for (int s = 0; s < 2; s++) {
      bf16x8 qf[2], kf[4];
      #pragma unroll
      for (int mt = 0; mt < 2; mt++) {
        int qrow = w * 32 + mt * 16 + r;
        int cb = (s * 4 + g) ^ (qrow & 7);
        qf[mt] = *(const bf16x8*)(Q_s + qrow * 128 + cb * 16);
      }
      #pragma unroll
      for (int nt = 0; nt < 4; nt++) {
        int krow = nt * 16 + r;
        int cb = (s * 4 + g) ^ (krow & 7);
        kf[nt] = *(const bf16x8*)(K_s + krow * 128 + cb * 16);
      }
      #pragma unroll
      for (int mt = 0; mt < 2; mt++)
        #pragma unroll
        for (int nt = 0; nt < 4; nt++)
          sa[mt][nt] = __builtin_amdgcn_mfma_f32_16x16x32_bf16(
              qf[mt], kf[nt], sa[mt][nt], 0, 0, 0);
    }

    // ---- online softmax in C-layout (row=(g*4+rr), col=nt*16+r) ----
    float ma[4];
    #pragma unroll
    for (int nt = 0; nt < 4; nt++)
      ma[nt] = maskAddG[tok0 + kt * 64 + nt * 16 + r];

    #pragma unroll
    for (int mt = 0; mt < 2; mt++) {
      #pragma unroll
      for (int rr = 0; rr < 4; rr++) {
        float v0 = sa[mt][0][rr] * 0.125f + ma[0];
        float v1 = sa[mt][1][rr] * 0.125f + ma[1];
        float v2 = sa[mt][2][rr] * 0.125f + ma[2];
        float v3 = sa[mt][3][rr] * 0.125f + ma[3];
        float mx = fmaxf(fmaxf(v0, v1), fmaxf(v2, v3));
        mx = fmaxf(mx, __shfl_xor(mx, 1));
        mx = fmaxf(mx, __shfl_xor(mx, 2));
        mx = fmaxf(mx, __shfl_xor(mx, 4));
        mx = fmaxf(mx, __shfl_xor(mx, 8));
        float mold = mstate[mt][rr];
        float mnew = fmaxf(mold, mx);
        float alpha = __expf(mold - mnew);
        float p0 = __expf(v0 - mnew);
        float p1 = __expf(v1 - mnew);
        float p2 = __expf(v2 - mnew);
        float p3 = __expf(v3 - mnew);
        float ps = p0 + p1 + p2 + p3;
        ps += __shfl_xor(ps, 1);
        ps += __shfl_xor(ps, 2);
        ps += __shfl_xor(ps, 4);
        ps += __shfl_xor(ps, 8);
        lstate[mt][rr] = lstate[mt][rr] * alpha + ps;
        mstate[mt][rr] = mnew;
        // rescale ONLY this row's accumulator component (bug fixed: was whole f32x4)
        #pragma unroll
        for (int dt = 0; dt < 4; dt++) o_acc[mt][dt][rr] *= alpha;
        // write P row (bf16, chunk-swizzled): qrow in [0,32)
        int qrow = mt * 16 + g * 4 + rr;
        int sz = qrow & 7;
        char* pr = Pw + qrow * 128;
        int kv0 = r;
        *(unsigned short*)(pr + ((((kv0) >> 3) ^ sz) << 4) + ((kv0 & 7) << 1)) = f2bf(p0);
        int kv1 = 16 + r;
        *(unsigned short*)(pr + ((((kv1) >> 3) ^ sz) << 4) + ((kv1 & 7) << 1)) = f2bf(p1);
        int kv2 = 32 + r;
        *(unsigned short*)(pr + ((((kv2) >> 3) ^ sz) << 4) + ((kv2 & 7) << 1)) = f2bf(p2);
        int kv3 = 48 + r;
        *(unsigned short*)(pr + ((((kv3) >> 3) ^ sz) << 4) + ((kv3 & 7) << 1)) = f2bf(p3);
      }
    }

    // ---- O += P V  (A=P from own wave's LDS region, B=V^T tile) ----
    #pragma unroll
    for (int s = 0; s < 2; s++) {
      bf16x8 pf[2], vf[4];
      #pragma unroll
      for (int mt = 0; mt < 2; mt++) {
        int prow = mt * 16 + r;
        int cb = (s * 4 + g) ^ (prow & 7);
        pf[mt] = *(const bf16x8*)(Pw + prow * 128 + cb * 16);
      }
      #pragma unroll
      for (int dt = 0; dt < 4; dt++) {
        int drow = dt * 16 + r;
        int cb = (s * 4 + g) ^ (drow & 7);
        vf[dt] = *(const bf16x8*)(V_s + drow * 128 + cb * 16);
      }
      #pragma unroll
      for (int mt = 0; mt < 2; mt++)
        #pragma unroll
        for (int dt = 0; dt < 4; dt++)
          o_acc[mt][dt] = __builtin_amdgcn_mfma_f32_16x16x32_bf16(
              pf[mt], vf[dt], o_acc[mt][dt], 0, 0, 0);
    }
  }

  // ---- epilogue: O / l -> av (bf16) ----
  #pragma unroll
  for (int mt = 0; mt < 2; mt++) {
    #pragma unroll
    for (int rr = 0; rr < 4; rr++) {
      float invl = 1.0f / lstate[mt][rr];
      size_t row = tok0 + (size_t)qt * 128 + w * 32 + mt * 16 + g * 4 + rr;
      #pragma unroll
      for (int dt = 0; dt < 4; dt++) {
        av[row * D_MODEL + h * 64 + dt * 16 + r] = f2bf(o_acc[mt][dt][rr] * invl);
      }
    }
  }
}

// ---------------- launch ----------------
extern "C" void kernel_launch(void* const* d_in, const int* in_sizes, int n_in,
                              void* d_out, int out_size, void* d_ws, size_t ws_size,
                              hipStream_t stream) {
  const float* x        = (const float*)d_in[0];
  const void*  mask     = d_in[1];
  const float* ln_in_w  = (const float*)d_in[2];
  const float* ln_in_b  = (const float*)d_in[3];
  const float* qkv_w    = (const float*)d_in[4];
  const float* qkv_b    = (const float*)d_in[5];
  const float* out_w    = (const float*)d_in[6];
  const float* out_b    = (const float*)d_in[7];
  const float* ln_out_w = (const float*)d_in[8];
  const float* ln_out_b = (const float*)d_in[9];
  float* out = (float*)d_out;

  const size_t MB = 1024 * 1024;
  char* ws = (char*)d_ws;
  unsigned short* xn      = (unsigned short*)(ws);             // 8 MB bf16
  unsigned short* qkv     = (unsigned short*)(ws + 8 * MB);    // 24 MB bf16
  unsigned short* Vt      = (unsigned short*)(ws + 32 * MB);   // 8 MB bf16
  unsigned short* av      = (unsigned short*)(ws + 40 * MB);   // 8 MB bf16
  float*          proj    = (float*)(ws + 48 * MB);            // 16 MB f32
  unsigned short* qkv_wT  = (unsigned short*)(ws + 64 * MB);   // 6 MB bf16
  unsigned short* out_wT  = (unsigned short*)(ws + 70 * MB);   // 2 MB bf16
  float*          maskAdd = (float*)(ws + 72 * MB);            // 16 KB
  int*            flag    = (int*)(ws + 72 * MB + 16384);

  mask_detect_kernel<<<1, 256, 0, stream>>>((const unsigned char*)mask, flag);
  mask_convert_kernel<<<(NTOK + 255) / 256, 256, 0, stream>>>(mask, flag, maskAdd);

  transpose_convert_kernel<<<dim3(3 * D_MODEL / 64, D_MODEL / 64), 256, 0, stream>>>(
      qkv_w, qkv_wT, D_MODEL, 3 * D_MODEL);
  transpose_convert_kernel<<<dim3(D_MODEL / 64, D_MODEL / 64), 256, 0, stream>>>(
      out_w, out_wT, D_MODEL, D_MODEL);

  ln_kernel<true><<<NTOK, 256, 0, stream>>>(x, ln_in_w, ln_in_b, xn);

  gemm_mfma_kernel<unsigned short><<<dim3(3 * D_MODEL / 128, NTOK / 128), 256, 0, stream>>>(
      xn, qkv_wT, qkv_b, qkv, NTOK, 3 * D_MODEL, D_MODEL);

  v_transpose_kernel<<<dim3(SEQ / 64, NH, NBATCH), 256, 0, stream>>>(qkv, Vt);

  attn_mfma_kernel<<<dim3(SEQ / 128, NH, NBATCH), 256, 0, stream>>>(
      qkv, Vt, maskAdd, av);

  gemm_mfma_kernel<float><<<dim3(D_MODEL / 128, NTOK / 128), 256, 0, stream>>>(
      av, out_wT, out_b, proj, NTOK, D_MODEL, D_MODEL);

  ln_kernel<false><<<NTOK, 256, 0, stream>>>(proj, ln_out_w, ln_out_b, out);
}

// Round 6
// 201.207 us; speedup vs baseline: 4.8738x; 1.1204x over previous
//
#include <hip/hip_runtime.h>
#include <math.h>

#define D_MODEL 1024
#define SEQ     2048
#define NBATCH  2
#define NTOK    (NBATCH * SEQ)
#define NH      16
#define HD      64

typedef float f32x4 __attribute__((ext_vector_type(4)));
typedef short bf16x8 __attribute__((ext_vector_type(8)));
typedef short bf16x4 __attribute__((ext_vector_type(4)));

__device__ __forceinline__ unsigned short f2bf(float f) {
  unsigned u = __builtin_bit_cast(unsigned, f);
  u += 0x7FFFu + ((u >> 16) & 1u);
  return (unsigned short)(u >> 16);
}

// Pinned unconditionally to the gfx90a-era builtin: it compiled on BOTH host
// and device passes in round 4. The new-style name is undeclared on host
// (round-5 evidence) and unvalidated on device.
__device__ __forceinline__ f32x4 mfma16(bf16x4 a, bf16x4 b, f32x4 c) {
  return __builtin_amdgcn_mfma_f32_16x16x16bf16_1k(a, b, c, 0, 0, 0);
}

__device__ __forceinline__ void gload16(const void* g, void* l) {
  __builtin_amdgcn_global_load_lds(
      (const __attribute__((address_space(1))) void*)g,
      (__attribute__((address_space(3))) void*)l, 16, 0, 0);
}

// ---------------- mask dtype detect / convert ----------------
__global__ void mask_detect_kernel(const unsigned char* __restrict__ m,
                                   int* __restrict__ flag) {
  __shared__ int c1s, c3s;
  if (threadIdx.x == 0) { c1s = 0; c3s = 0; }
  __syncthreads();
  int c1 = 0, c3 = 0;
  for (int i = threadIdx.x; i < NTOK; i += 256) {
    unsigned char v = m[i];
    if (v) {
      if ((i & 3) == 1) c1++;
      if ((i & 3) == 3) c3++;
    }
  }
  if (c1) atomicAdd(&c1s, c1);
  if (c3) atomicAdd(&c3s, c3);
  __syncthreads();
  if (threadIdx.x == 0) *flag = (c1s > 0) ? 1 : ((c3s > 0) ? 2 : 0);
}

// multiplicative mask: 1.0 keep, 0.0 drop (applied to P after exp)
__global__ void mask_convert_kernel(const void* __restrict__ m,
                                    const int* __restrict__ flag,
                                    float* __restrict__ maskMul) {
  int i = blockIdx.x * 256 + threadIdx.x;
  if (i >= NTOK) return;
  int f = *flag;
  bool on;
  if (f == 1)      on = ((const unsigned char*)m)[i] != 0;
  else if (f == 2) on = ((const float*)m)[i] != 0.0f;
  else             on = ((const int*)m)[i] != 0;
  maskMul[i] = on ? 1.0f : 0.0f;
}

// ---------------- LayerNorm ----------------
__device__ inline float block_reduce_sum(float v, float* red) {
  #pragma unroll
  for (int s = 1; s < 64; s <<= 1) v += __shfl_xor(v, s);
  int wid = threadIdx.x >> 6, lane = threadIdx.x & 63;
  if (lane == 0) red[wid] = v;
  __syncthreads();
  float t = red[0] + red[1] + red[2] + red[3];
  __syncthreads();
  return t;
}

template <bool BF16OUT>
__global__ __launch_bounds__(256) void ln_kernel(const float* __restrict__ x,
                                                 const float* __restrict__ w,
                                                 const float* __restrict__ b,
                                                 void* __restrict__ yv) {
  __shared__ float red[4];
  int row = blockIdx.x;
  int tid = threadIdx.x;
  float4 v = ((const float4*)(x + (size_t)row * D_MODEL))[tid];
  float s = v.x + v.y + v.z + v.w;
  float tot = block_reduce_sum(s, red);
  float mu = tot * (1.0f / D_MODEL);
  float dx = v.x - mu, dy = v.y - mu, dz = v.z - mu, dw = v.w - mu;
  float sq = dx * dx + dy * dy + dz * dz + dw * dw;
  float tot2 = block_reduce_sum(sq, red);
  float inv = rsqrtf(tot2 * (1.0f / D_MODEL) + 1e-5f);
  float4 wv = ((const float4*)w)[tid];
  float4 bv = ((const float4*)b)[tid];
  float4 o;
  o.x = dx * inv * wv.x + bv.x;
  o.y = dy * inv * wv.y + bv.y;
  o.z = dz * inv * wv.z + bv.z;
  o.w = dw * inv * wv.w + bv.w;
  if constexpr (BF16OUT) {
    ushort4 o4 = {f2bf(o.x), f2bf(o.y), f2bf(o.z), f2bf(o.w)};
    ((ushort4*)((unsigned short*)yv + (size_t)row * D_MODEL))[tid] = o4;
  } else {
    ((float4*)((float*)yv + (size_t)row * D_MODEL))[tid] = o;
  }
}

// ---------------- weight transpose+convert: W[K][N] f32 -> WT[N][K] bf16 ----------------
__global__ __launch_bounds__(256) void transpose_convert_kernel(
    const float* __restrict__ W, unsigned short* __restrict__ WT, int K, int N) {
  __shared__ float t[64][65];
  int k0 = blockIdx.y * 64, n0 = blockIdx.x * 64;
  int tid = threadIdx.x;
  int rr = tid >> 4, cc = (tid & 15) * 4;
  #pragma unroll
  for (int i = 0; i < 4; i++) {
    int rk = i * 16 + rr;
    float4 v = *(const float4*)&W[(size_t)(k0 + rk) * N + n0 + cc];
    t[rk][cc + 0] = v.x; t[rk][cc + 1] = v.y; t[rk][cc + 2] = v.z; t[rk][cc + 3] = v.w;
  }
  __syncthreads();
  #pragma unroll
  for (int i = 0; i < 4; i++) {
    int rn = i * 16 + rr;
    ushort4 o = {f2bf(t[cc + 0][rn]), f2bf(t[cc + 1][rn]),
                 f2bf(t[cc + 2][rn]), f2bf(t[cc + 3][rn])};
    *(ushort4*)&WT[(size_t)(n0 + rn) * K + k0 + cc] = o;
  }
}

// ---------------- V transpose: qkv[tok][2048+h*64+d] bf16 -> Vt[(n*16+h)*64+d][s] ----------------
__global__ __launch_bounds__(256) void v_transpose_kernel(
    const unsigned short* __restrict__ qkv, unsigned short* __restrict__ Vt) {
  __shared__ unsigned short t[64][66];
  int s0 = blockIdx.x * 64;
  int h = blockIdx.y, n = blockIdx.z;
  int tid = threadIdx.x;
  #pragma unroll
  for (int i = 0; i < 2; i++) {
    int ch = i * 256 + tid;
    int sr = ch >> 3, c8 = (ch & 7) * 8;
    const unsigned short* src =
        qkv + (size_t)(n * SEQ + s0 + sr) * 3072 + 2048 + h * 64 + c8;
    uint4 v = *(const uint4*)src;
    unsigned short tmp[8];
    *(uint4*)tmp = v;
    #pragma unroll
    for (int j = 0; j < 8; j++) t[sr][c8 + j] = tmp[j];
  }
  __syncthreads();
  #pragma unroll
  for (int i = 0; i < 2; i++) {
    int ch = i * 256 + tid;
    int d = ch >> 3, s8 = (ch & 7) * 8;
    unsigned short tmp[8];
    #pragma unroll
    for (int j = 0; j < 8; j++) tmp[j] = t[s8 + j][d];
    unsigned short* dst =
        Vt + ((size_t)((n * NH + h) * HD) + d) * SEQ + s0 + s8;
    *(uint4*)dst = *(const uint4*)tmp;
  }
}

// ---------------- bf16 MFMA GEMM (unchanged, verified) ----------------
template <typename OutT>
__global__ __launch_bounds__(256) void gemm_mfma_kernel(
    const unsigned short* __restrict__ A, const unsigned short* __restrict__ BT,
    const float* __restrict__ bias, OutT* __restrict__ C, int M, int N, int K) {
  __shared__ __align__(16) char As[16384];
  __shared__ __align__(16) char Bs[16384];
  int tid = threadIdx.x;
  int lane = tid & 63, w = tid >> 6;
  int r = lane & 15, g = lane >> 4;
  int wm = w >> 1, wn = w & 1;
  int m0 = blockIdx.y * 128, n0 = blockIdx.x * 128;
  f32x4 acc[4][4] = {};

  const char* Ab = (const char*)A;
  const char* Bb = (const char*)BT;
  for (int k0 = 0; k0 < K; k0 += 64) {
    __syncthreads();
    #pragma unroll
    for (int i = 0; i < 4; i++) {
      int chb = i * 256 + w * 64;
      int ch = chb + lane;
      int row = ch >> 3, cb = (ch & 7) ^ (row & 7);
      gload16(Ab + (((size_t)(m0 + row) * K + k0) << 1) + (cb << 4), As + chb * 16);
      gload16(Bb + (((size_t)(n0 + row) * K + k0) << 1) + (cb << 4), Bs + chb * 16);
    }
    __syncthreads();
    #pragma unroll
    for (int s = 0; s < 2; s++) {
      bf16x8 af[4], bfr[4];
      #pragma unroll
      for (int mt = 0; mt < 4; mt++) {
        int arow = wm * 64 + mt * 16 + r;
        int cb = (s * 4 + g) ^ (arow & 7);
        af[mt] = *(const bf16x8*)(As + arow * 128 + cb * 16);
      }
      #pragma unroll
      for (int nt = 0; nt < 4; nt++) {
        int brow = wn * 64 + nt * 16 + r;
        int cb = (s * 4 + g) ^ (brow & 7);
        bfr[nt] = *(const bf16x8*)(Bs + brow * 128 + cb * 16);
      }
      #pragma unroll
      for (int mt = 0; mt < 4; mt++)
        #pragma unroll
        for (int nt = 0; nt < 4; nt++)
          acc[mt][nt] = __builtin_amdgcn_mfma_f32_16x16x32_bf16(
              af[mt], bfr[nt], acc[mt][nt], 0, 0, 0);
    }
  }
  #pragma unroll
  for (int nt = 0; nt < 4; nt++) {
    int col = n0 + wn * 64 + nt * 16 + r;
    float bv = bias[col];
    #pragma unroll
    for (int mt = 0; mt < 4; mt++) {
      #pragma unroll
      for (int rr = 0; rr < 4; rr++) {
        int row = m0 + wm * 64 + mt * 16 + g * 4 + rr;
        float v = acc[mt][nt][rr] + bv;
        if constexpr (sizeof(OutT) == 2) {
          C[(size_t)row * N + col] = (OutT)f2bf(v);
        } else {
          C[(size_t)row * N + col] = v;
        }
      }
    }
  }
}

// ---------------- MFMA flash attention, swapped-operand in-register softmax ----------------
// grid (SEQ/128, NH, NBATCH), 256 thr = 4 waves; wave w owns q-rows [w*32, w*32+32).
// S^T = mfma(K, Q): lane owns P-row for q = lane&15 (per mt block), kv = 16nt+4g+rr.
// O^T = mfma(V^T, P^T) with K=16 MFMA: B-frag k = 4g+j == lane's own kv. No P LDS.
// A/B fragments share the same (g,j)->k map, so internal k-permutations cancel.
// All numerics finite: mstate init -3e4 (never +-inf), invl guarded.
__global__ __launch_bounds__(256) void attn_mfma_kernel(
    const unsigned short* __restrict__ qkv, const unsigned short* __restrict__ Vt,
    const float* __restrict__ maskMulG, unsigned short* __restrict__ av) {
  __shared__ __align__(16) char Q_s[16384];  // [qrow 128][d 64] bf16, chunk-swizzled
  __shared__ __align__(16) char K_s[8192];   // [kv 64][d 64]
  __shared__ __align__(16) char V_s[8192];   // [d 64][kv 64]  (V^T)
  int tid = threadIdx.x;
  int lane = tid & 63, w = tid >> 6;
  int r = lane & 15, g = lane >> 4;
  int qt = blockIdx.x, h = blockIdx.y, bn = blockIdx.z;
  size_t tok0 = (size_t)bn * SEQ;

  const char* qb = (const char*)qkv + (((tok0 + qt * 128) * 3072) + h * 64) * 2;
  #pragma unroll
  for (int i = 0; i < 4; i++) {
    int chb = i * 256 + w * 64;
    int ch = chb + lane;
    int row = ch >> 3, cb = (ch & 7) ^ (row & 7);
    gload16(qb + (size_t)row * 6144 + (cb << 4), Q_s + chb * 16);
  }

  float mstate[2] = {-30000.0f, -30000.0f};
  float lstate[2] = {0.f, 0.f};
  f32x4 o_acc[2][4] = {};  // [mt][dt]: d = 16*dt + 4*g + rr, q = mt*16 + r (in wave block)

  const float CC = 0.18033688011112042f;  // 0.125 * log2(e)

  for (int kt = 0; kt < SEQ / 64; kt++) {
    __syncthreads();  // all waves done reading K_s/V_s from previous tile
    const char* kb = (const char*)qkv + (((tok0 + kt * 64) * 3072) + 1024 + h * 64) * 2;
    const char* vb = (const char*)Vt + ((((size_t)(bn * NH + h) * HD) * SEQ) + kt * 64) * 2;
    #pragma unroll
    for (int i = 0; i < 2; i++) {
      int chb = i * 256 + w * 64;
      int ch = chb + lane;
      int row = ch >> 3, cb = (ch & 7) ^ (row & 7);
      gload16(kb + (size_t)row * 6144 + (cb << 4), K_s + chb * 16);
      gload16(vb + (size_t)row * 4096 + (cb << 4), V_s + chb * 16);
    }
    // mask (multiplicative), indexed by this lane's kv values: kv = 16*nt + 4*g + rr
    float4 mmv[4];
    #pragma unroll
    for (int nt = 0; nt < 4; nt++)
      mmv[nt] = *(const float4*)(maskMulG + tok0 + kt * 64 + nt * 16 + 4 * g);
    __syncthreads();  // staging complete

    // ---- S^T = K Q^T : sa[mt][nt], row=kv (nt block), col=q (mt block) ----
    f32x4 sa[2][4] = {};
    #pragma unroll
    for (int s = 0; s < 2; s++) {
      bf16x8 qf[2], kf[4];
      #pragma unroll
      for (int mt = 0; mt < 2; mt++) {
        int qrow = w * 32 + mt * 16 + r;
        int cb = (s * 4 + g) ^ (qrow & 7);
        qf[mt] = *(const bf16x8*)(Q_s + qrow * 128 + cb * 16);
      }
      #pragma unroll
      for (int nt = 0; nt < 4; nt++) {
        int krow = nt * 16 + r;
        int cb = (s * 4 + g) ^ (krow & 7);
        kf[nt] = *(const bf16x8*)(K_s + krow * 128 + cb * 16);
      }
      #pragma unroll
      for (int mt = 0; mt < 2; mt++)
        #pragma unroll
        for (int nt = 0; nt < 4; nt++)
          sa[mt][nt] = __builtin_amdgcn_mfma_f32_16x16x32_bf16(
              kf[nt], qf[mt], sa[mt][nt], 0, 0, 0);
    }

    // ---- V^T fragments for PV (shared across mt): A[row=d][k=kv], K=16 slices ----
    bf16x4 vf[4][4];  // [s4][dt]
    #pragma unroll
    for (int s4 = 0; s4 < 4; s4++)
      #pragma unroll
      for (int dt = 0; dt < 4; dt++) {
        int row = dt * 16 + r;
        int chunk = (2 * s4 + (g >> 1)) ^ (row & 7);
        vf[s4][dt] = *(const bf16x4*)(V_s + row * 128 + chunk * 16 + (g & 1) * 8);
      }

    // ---- per-mt: in-register softmax + PV ----
    #pragma unroll
    for (int mt = 0; mt < 2; mt++) {
      float sv[16];
      #pragma unroll
      for (int nt = 0; nt < 4; nt++)
        #pragma unroll
        for (int rr = 0; rr < 4; rr++) sv[nt * 4 + rr] = sa[mt][nt][rr];
      float mx = sv[0];
      #pragma unroll
      for (int j = 1; j < 16; j++) mx = fmaxf(mx, sv[j]);
      mx = fmaxf(mx, __shfl_xor(mx, 16));
      mx = fmaxf(mx, __shfl_xor(mx, 32));
      float mold = mstate[mt];
      float mnew = fmaxf(mold, mx);
      float mc = mnew * CC;
      float alpha = exp2f(mold * CC - mc);  // first tile: underflows to 0, finite path
      float p[16];
      float rs = 0.f;
      #pragma unroll
      for (int nt = 0; nt < 4; nt++) {
        float m0 = ((const float*)&mmv[nt])[0];
        float m1 = ((const float*)&mmv[nt])[1];
        float m2 = ((const float*)&mmv[nt])[2];
        float m3 = ((const float*)&mmv[nt])[3];
        p[nt * 4 + 0] = exp2f(fmaf(sv[nt * 4 + 0], CC, -mc)) * m0;
        p[nt * 4 + 1] = exp2f(fmaf(sv[nt * 4 + 1], CC, -mc)) * m1;
        p[nt * 4 + 2] = exp2f(fmaf(sv[nt * 4 + 2], CC, -mc)) * m2;
        p[nt * 4 + 3] = exp2f(fmaf(sv[nt * 4 + 3], CC, -mc)) * m3;
        rs += p[nt * 4 + 0] + p[nt * 4 + 1] + p[nt * 4 + 2] + p[nt * 4 + 3];
      }
      rs += __shfl_xor(rs, 16);
      rs += __shfl_xor(rs, 32);
      lstate[mt] = lstate[mt] * alpha + rs;
      mstate[mt] = mnew;
      #pragma unroll
      for (int dt = 0; dt < 4; dt++) o_acc[mt][dt] *= alpha;

      // pack P^T B-fragments with the proven f2bf (RNE): slice s4 = lane's own
      // kv = 16*s4 + 4g + j. No inline asm.
      bf16x4 bq[4];
      #pragma unroll
      for (int s4 = 0; s4 < 4; s4++) {
        uint2 u;
        u.x = (unsigned)f2bf(p[4 * s4 + 0]) | ((unsigned)f2bf(p[4 * s4 + 1]) << 16);
        u.y = (unsigned)f2bf(p[4 * s4 + 2]) | ((unsigned)f2bf(p[4 * s4 + 3]) << 16);
        bq[s4] = __builtin_bit_cast(bf16x4, u);
      }
      #pragma unroll
      for (int s4 = 0; s4 < 4; s4++)
        #pragma unroll
        for (int dt = 0; dt < 4; dt++)
          o_acc[mt][dt] = mfma16(vf[s4][dt], bq[s4], o_acc[mt][dt]);
    }
  }

  // ---- epilogue: O^T frag -> av[q][h*64 + d], d = 16dt + 4g + rr ----
  #pragma unroll
  for (int mt = 0; mt < 2; mt++) {
    float invl = 1.0f / fmaxf(lstate[mt], 1e-30f);
    size_t qrow = tok0 + (size_t)qt * 128 + w * 32 + mt * 16 + r;
    unsigned short* base = av + qrow * D_MODEL + h * 64;
    #pragma unroll
    for (int dt = 0; dt < 4; dt++) {
      ushort4 o4 = {f2bf(o_acc[mt][dt][0] * invl), f2bf(o_acc[mt][dt][1] * invl),
                    f2bf(o_acc[mt][dt][2] * invl), f2bf(o_acc[mt][dt][3] * invl)};
      *(ushort4*)(base + dt * 16 + 4 * g) = o4;
    }
  }
}

// ---------------- launch ----------------
extern "C" void kernel_launch(void* const* d_in, const int* in_sizes, int n_in,
                              void* d_out, int out_size, void* d_ws, size_t ws_size,
                              hipStream_t stream) {
  const float* x        = (const float*)d_in[0];
  const void*  mask     = d_in[1];
  const float* ln_in_w  = (const float*)d_in[2];
  const float* ln_in_b  = (const float*)d_in[3];
  const float* qkv_w    = (const float*)d_in[4];
  const float* qkv_b    = (const float*)d_in[5];
  const float* out_w    = (const float*)d_in[6];
  const float* out_b    = (const float*)d_in[7];
  const float* ln_out_w = (const float*)d_in[8];
  const float* ln_out_b = (const float*)d_in[9];
  float* out = (float*)d_out;

  const size_t MB = 1024 * 1024;
  char* ws = (char*)d_ws;
  unsigned short* xn      = (unsigned short*)(ws);             // 8 MB bf16
  unsigned short* qkv     = (unsigned short*)(ws + 8 * MB);    // 24 MB bf16
  unsigned short* Vt      = (unsigned short*)(ws + 32 * MB);   // 8 MB bf16
  unsigned short* av      = (unsigned short*)(ws + 40 * MB);   // 8 MB bf16
  float*          proj    = (float*)(ws + 48 * MB);            // 16 MB f32
  unsigned short* qkv_wT  = (unsigned short*)(ws + 64 * MB);   // 6 MB bf16
  unsigned short* out_wT  = (unsigned short*)(ws + 70 * MB);   // 2 MB bf16
  float*          maskMul = (float*)(ws + 72 * MB);            // 16 KB
  int*            flag    = (int*)(ws + 72 * MB + 16384);

  mask_detect_kernel<<<1, 256, 0, stream>>>((const unsigned char*)mask, flag);
  mask_convert_kernel<<<(NTOK + 255) / 256, 256, 0, stream>>>(mask, flag, maskMul);

  transpose_convert_kernel<<<dim3(3 * D_MODEL / 64, D_MODEL / 64), 256, 0, stream>>>(
      qkv_w, qkv_wT, D_MODEL, 3 * D_MODEL);
  transpose_convert_kernel<<<dim3(D_MODEL / 64, D_MODEL / 64), 256, 0, stream>>>(
      out_w, out_wT, D_MODEL, D_MODEL);

  ln_kernel<true><<<NTOK, 256, 0, stream>>>(x, ln_in_w, ln_in_b, xn);

  gemm_mfma_kernel<unsigned short><<<dim3(3 * D_MODEL / 128, NTOK / 128), 256, 0, stream>>>(
      xn, qkv_wT, qkv_b, qkv, NTOK, 3 * D_MODEL, D_MODEL);

  v_transpose_kernel<<<dim3(SEQ / 64, NH, NBATCH), 256, 0, stream>>>(qkv, Vt);

  attn_mfma_kernel<<<dim3(SEQ / 128, NH, NBATCH), 256, 0, stream>>>(
      qkv, Vt, maskMul, av);

  gemm_mfma_kernel<float><<<dim3(D_MODEL / 128, NTOK / 128), 256, 0, stream>>>(
      av, out_wT, out_b, proj, NTOK, D_MODEL, D_MODEL);

  ln_kernel<false><<<NTOK, 256, 0, stream>>>(proj, ln_out_w, ln_out_b, out);
}

// Round 7
// 178.592 us; speedup vs baseline: 5.4910x; 1.1266x over previous
//
#include <hip/hip_runtime.h>
#include <math.h>

#define D_MODEL 1024
#define SEQ     2048
#define NBATCH  2
#define NTOK    (NBATCH * SEQ)
#define NH      16
#define HD      64

typedef float f32x4 __attribute__((ext_vector_type(4)));
typedef short bf16x8 __attribute__((ext_vector_type(8)));
typedef short bf16x4 __attribute__((ext_vector_type(4)));

__device__ __forceinline__ unsigned short f2bf(float f) {
  unsigned u = __builtin_bit_cast(unsigned, f);
  u += 0x7FFFu + ((u >> 16) & 1u);
  return (unsigned short)(u >> 16);
}

// guide-validated on MI355X (m214v22): packs 2 f32 -> 2 bf16 in one VALU op
__device__ __forceinline__ unsigned cvt_pk_bf16(float lo, float hi) {
  unsigned d;
  asm("v_cvt_pk_bf16_f32 %0, %1, %2" : "=v"(d) : "v"(lo), "v"(hi));
  return d;
}

__device__ __forceinline__ f32x4 mfma16(bf16x4 a, bf16x4 b, f32x4 c) {
  return __builtin_amdgcn_mfma_f32_16x16x16bf16_1k(a, b, c, 0, 0, 0);
}

__device__ __forceinline__ void gload16(const void* g, void* l) {
  __builtin_amdgcn_global_load_lds(
      (const __attribute__((address_space(1))) void*)g,
      (__attribute__((address_space(3))) void*)l, 16, 0, 0);
}

// ---------------- mask dtype detect / convert ----------------
__global__ void mask_detect_kernel(const unsigned char* __restrict__ m,
                                   int* __restrict__ flag) {
  __shared__ int c1s, c3s;
  if (threadIdx.x == 0) { c1s = 0; c3s = 0; }
  __syncthreads();
  int c1 = 0, c3 = 0;
  for (int i = threadIdx.x; i < NTOK; i += 256) {
    unsigned char v = m[i];
    if (v) {
      if ((i & 3) == 1) c1++;
      if ((i & 3) == 3) c3++;
    }
  }
  if (c1) atomicAdd(&c1s, c1);
  if (c3) atomicAdd(&c3s, c3);
  __syncthreads();
  if (threadIdx.x == 0) *flag = (c1s > 0) ? 1 : ((c3s > 0) ? 2 : 0);
}

__global__ void mask_convert_kernel(const void* __restrict__ m,
                                    const int* __restrict__ flag,
                                    float* __restrict__ maskMul) {
  int i = blockIdx.x * 256 + threadIdx.x;
  if (i >= NTOK) return;
  int f = *flag;
  bool on;
  if (f == 1)      on = ((const unsigned char*)m)[i] != 0;
  else if (f == 2) on = ((const float*)m)[i] != 0.0f;
  else             on = ((const int*)m)[i] != 0;
  maskMul[i] = on ? 1.0f : 0.0f;
}

// ---------------- LayerNorm ----------------
__device__ inline float block_reduce_sum(float v, float* red) {
  #pragma unroll
  for (int s = 1; s < 64; s <<= 1) v += __shfl_xor(v, s);
  int wid = threadIdx.x >> 6, lane = threadIdx.x & 63;
  if (lane == 0) red[wid] = v;
  __syncthreads();
  float t = red[0] + red[1] + red[2] + red[3];
  __syncthreads();
  return t;
}

template <bool BF16OUT>
__global__ __launch_bounds__(256) void ln_kernel(const float* __restrict__ x,
                                                 const float* __restrict__ w,
                                                 const float* __restrict__ b,
                                                 void* __restrict__ yv) {
  __shared__ float red[4];
  int row = blockIdx.x;
  int tid = threadIdx.x;
  float4 v = ((const float4*)(x + (size_t)row * D_MODEL))[tid];
  float s = v.x + v.y + v.z + v.w;
  float tot = block_reduce_sum(s, red);
  float mu = tot * (1.0f / D_MODEL);
  float dx = v.x - mu, dy = v.y - mu, dz = v.z - mu, dw = v.w - mu;
  float sq = dx * dx + dy * dy + dz * dz + dw * dw;
  float tot2 = block_reduce_sum(sq, red);
  float inv = rsqrtf(tot2 * (1.0f / D_MODEL) + 1e-5f);
  float4 wv = ((const float4*)w)[tid];
  float4 bv = ((const float4*)b)[tid];
  float4 o;
  o.x = dx * inv * wv.x + bv.x;
  o.y = dy * inv * wv.y + bv.y;
  o.z = dz * inv * wv.z + bv.z;
  o.w = dw * inv * wv.w + bv.w;
  if constexpr (BF16OUT) {
    ushort4 o4 = {f2bf(o.x), f2bf(o.y), f2bf(o.z), f2bf(o.w)};
    ((ushort4*)((unsigned short*)yv + (size_t)row * D_MODEL))[tid] = o4;
  } else {
    ((float4*)((float*)yv + (size_t)row * D_MODEL))[tid] = o;
  }
}

// ---------------- weight transpose+convert: W[K][N] f32 -> WT[N][K] bf16 ----------------
__global__ __launch_bounds__(256) void transpose_convert_kernel(
    const float* __restrict__ W, unsigned short* __restrict__ WT, int K, int N) {
  __shared__ float t[64][65];
  int k0 = blockIdx.y * 64, n0 = blockIdx.x * 64;
  int tid = threadIdx.x;
  int rr = tid >> 4, cc = (tid & 15) * 4;
  #pragma unroll
  for (int i = 0; i < 4; i++) {
    int rk = i * 16 + rr;
    float4 v = *(const float4*)&W[(size_t)(k0 + rk) * N + n0 + cc];
    t[rk][cc + 0] = v.x; t[rk][cc + 1] = v.y; t[rk][cc + 2] = v.z; t[rk][cc + 3] = v.w;
  }
  __syncthreads();
  #pragma unroll
  for (int i = 0; i < 4; i++) {
    int rn = i * 16 + rr;
    ushort4 o = {f2bf(t[cc + 0][rn]), f2bf(t[cc + 1][rn]),
                 f2bf(t[cc + 2][rn]), f2bf(t[cc + 3][rn])};
    *(ushort4*)&WT[(size_t)(n0 + rn) * K + k0 + cc] = o;
  }
}

// ---------------- V transpose: qkv[tok][2048+h*64+d] bf16 -> Vt[(n*16+h)*64+d][s] ----------------
__global__ __launch_bounds__(256) void v_transpose_kernel(
    const unsigned short* __restrict__ qkv, unsigned short* __restrict__ Vt) {
  __shared__ unsigned short t[64][66];
  int s0 = blockIdx.x * 64;
  int h = blockIdx.y, n = blockIdx.z;
  int tid = threadIdx.x;
  #pragma unroll
  for (int i = 0; i < 2; i++) {
    int ch = i * 256 + tid;
    int sr = ch >> 3, c8 = (ch & 7) * 8;
    const unsigned short* src =
        qkv + (size_t)(n * SEQ + s0 + sr) * 3072 + 2048 + h * 64 + c8;
    uint4 v = *(const uint4*)src;
    unsigned short tmp[8];
    *(uint4*)tmp = v;
    #pragma unroll
    for (int j = 0; j < 8; j++) t[sr][c8 + j] = tmp[j];
  }
  __syncthreads();
  #pragma unroll
  for (int i = 0; i < 2; i++) {
    int ch = i * 256 + tid;
    int d = ch >> 3, s8 = (ch & 7) * 8;
    unsigned short tmp[8];
    #pragma unroll
    for (int j = 0; j < 8; j++) tmp[j] = t[s8 + j][d];
    unsigned short* dst =
        Vt + ((size_t)((n * NH + h) * HD) + d) * SEQ + s0 + s8;
    *(uint4*)dst = *(const uint4*)tmp;
  }
}

// ---------------- bf16 MFMA GEMM (unchanged, verified) ----------------
template <typename OutT>
__global__ __launch_bounds__(256) void gemm_mfma_kernel(
    const unsigned short* __restrict__ A, const unsigned short* __restrict__ BT,
    const float* __restrict__ bias, OutT* __restrict__ C, int M, int N, int K) {
  __shared__ __align__(16) char As[16384];
  __shared__ __align__(16) char Bs[16384];
  int tid = threadIdx.x;
  int lane = tid & 63, w = tid >> 6;
  int r = lane & 15, g = lane >> 4;
  int wm = w >> 1, wn = w & 1;
  int m0 = blockIdx.y * 128, n0 = blockIdx.x * 128;
  f32x4 acc[4][4] = {};

  const char* Ab = (const char*)A;
  const char* Bb = (const char*)BT;
  for (int k0 = 0; k0 < K; k0 += 64) {
    __syncthreads();
    #pragma unroll
    for (int i = 0; i < 4; i++) {
      int chb = i * 256 + w * 64;
      int ch = chb + lane;
      int row = ch >> 3, cb = (ch & 7) ^ (row & 7);
      gload16(Ab + (((size_t)(m0 + row) * K + k0) << 1) + (cb << 4), As + chb * 16);
      gload16(Bb + (((size_t)(n0 + row) * K + k0) << 1) + (cb << 4), Bs + chb * 16);
    }
    __syncthreads();
    #pragma unroll
    for (int s = 0; s < 2; s++) {
      bf16x8 af[4], bfr[4];
      #pragma unroll
      for (int mt = 0; mt < 4; mt++) {
        int arow = wm * 64 + mt * 16 + r;
        int cb = (s * 4 + g) ^ (arow & 7);
        af[mt] = *(const bf16x8*)(As + arow * 128 + cb * 16);
      }
      #pragma unroll
      for (int nt = 0; nt < 4; nt++) {
        int brow = wn * 64 + nt * 16 + r;
        int cb = (s * 4 + g) ^ (brow & 7);
        bfr[nt] = *(const bf16x8*)(Bs + brow * 128 + cb * 16);
      }
      #pragma unroll
      for (int mt = 0; mt < 4; mt++)
        #pragma unroll
        for (int nt = 0; nt < 4; nt++)
          acc[mt][nt] = __builtin_amdgcn_mfma_f32_16x16x32_bf16(
              af[mt], bfr[nt], acc[mt][nt], 0, 0, 0);
    }
  }
  #pragma unroll
  for (int nt = 0; nt < 4; nt++) {
    int col = n0 + wn * 64 + nt * 16 + r;
    float bv = bias[col];
    #pragma unroll
    for (int mt = 0; mt < 4; mt++) {
      #pragma unroll
      for (int rr = 0; rr < 4; rr++) {
        int row = m0 + wm * 64 + mt * 16 + g * 4 + rr;
        float v = acc[mt][nt][rr] + bv;
        if constexpr (sizeof(OutT) == 2) {
          C[(size_t)row * N + col] = (OutT)f2bf(v);
        } else {
          C[(size_t)row * N + col] = v;
        }
      }
    }
  }
}

// ---------------- MFMA flash attention: 8 waves, dbuf K/V, defer-max ----------------
// grid (SEQ/128, NH, NBATCH), 512 thr = 8 waves; wave w owns q-rows [w*16, w*16+16).
// S^T = mfma(K, Q): lane owns the P-row for q = lane&15; kv = 16nt + 4g + rr.
// O^T = mfma16(V^T, P^T): B-frag k = 4g+j == lane's own kv. No P LDS round-trip.
__global__ __launch_bounds__(512, 4) void attn_mfma_kernel(
    const unsigned short* __restrict__ qkv, const unsigned short* __restrict__ Vt,
    const float* __restrict__ maskMulG, unsigned short* __restrict__ av) {
  __shared__ __align__(16) char Q_s[16384];     // [qrow 128][d 64] bf16, chunk-swizzled
  __shared__ __align__(16) char K_s[2][8192];   // dbuf [kv 64][d 64]
  __shared__ __align__(16) char V_s[2][8192];   // dbuf [d 64][kv 64] (V^T)
  int tid = threadIdx.x;
  int lane = tid & 63, w = tid >> 6;
  int r = lane & 15, g = lane >> 4;
  int qt = blockIdx.x, h = blockIdx.y, bn = blockIdx.z;
  size_t tok0 = (size_t)bn * SEQ;

  const char* qb = (const char*)qkv + (((tok0 + qt * 128) * 3072) + h * 64) * 2;
  const char* kb0 = (const char*)qkv + ((tok0 * 3072) + 1024 + h * 64) * 2;
  const char* vb0 = (const char*)Vt + (((size_t)(bn * NH + h) * HD) * SEQ) * 2;

  // Q staging: 1024 chunks over 8 waves
  #pragma unroll
  for (int i = 0; i < 2; i++) {
    int chb = i * 512 + w * 64;
    int ch = chb + lane;
    int row = ch >> 3, cb = (ch & 7) ^ (row & 7);
    gload16(qb + (size_t)row * 6144 + (cb << 4), Q_s + chb * 16);
  }
  // K/V tile staging: 512 chunks each, 1 gload per lane each
  auto stage_kv = [&](int kt, int buf) {
    int chb = w * 64;
    int ch = chb + lane;
    int row = ch >> 3, cb = (ch & 7) ^ (row & 7);
    gload16(kb0 + (size_t)(kt * 64 + row) * 6144 + (cb << 4), K_s[buf] + chb * 16);
    gload16(vb0 + (size_t)row * 4096 + (size_t)kt * 128 + (cb << 4), V_s[buf] + chb * 16);
  };
  stage_kv(0, 0);
  __syncthreads();

  float mstate = -30000.0f;
  float lstate = 0.f;
  f32x4 o_acc[4] = {};  // [dt]: d = 16*dt + 4*g + rr, q = w*16 + r

  const float CC = 0.18033688011112042f;   // 0.125 * log2(e)
  const float DEFER = 44.3614195558365f;   // 8 / CC (raw-score units)

  for (int kt = 0; kt < SEQ / 64; kt++) {
    int cur = kt & 1;
    // mask loads FIRST (so their waitcnt doesn't drain the prefetch gloads)
    float4 mmv[4];
    #pragma unroll
    for (int nt = 0; nt < 4; nt++)
      mmv[nt] = *(const float4*)(maskMulG + tok0 + kt * 64 + nt * 16 + 4 * g);
    // prefetch next K/V tile into the other buffer
    if (kt + 1 < SEQ / 64) stage_kv(kt + 1, cur ^ 1);

    // ---- S^T = K Q^T : sa[nt], row(kv) = nt*16 + 4g+rr, col(q) = r ----
    f32x4 sa[4] = {};
    #pragma unroll
    for (int s = 0; s < 2; s++) {
      int qrow = w * 16 + r;
      int cbq = (s * 4 + g) ^ (qrow & 7);
      bf16x8 qf = *(const bf16x8*)(Q_s + qrow * 128 + cbq * 16);
      #pragma unroll
      for (int nt = 0; nt < 4; nt++) {
        int krow = nt * 16 + r;
        int cb = (s * 4 + g) ^ (krow & 7);
        bf16x8 kf = *(const bf16x8*)(K_s[cur] + krow * 128 + cb * 16);
        sa[nt] = __builtin_amdgcn_mfma_f32_16x16x32_bf16(kf, qf, sa[nt], 0, 0, 0);
      }
    }

    // ---- in-register softmax (lane owns one q-row's 16 kv values) ----
    float sv[16];
    #pragma unroll
    for (int nt = 0; nt < 4; nt++)
      #pragma unroll
      for (int rr = 0; rr < 4; rr++) sv[nt * 4 + rr] = sa[nt][rr];
    // balanced max tree
    float m01 = fmaxf(sv[0], sv[1]),   m23 = fmaxf(sv[2], sv[3]);
    float m45 = fmaxf(sv[4], sv[5]),   m67 = fmaxf(sv[6], sv[7]);
    float m89 = fmaxf(sv[8], sv[9]),   mab = fmaxf(sv[10], sv[11]);
    float mcd = fmaxf(sv[12], sv[13]), mef = fmaxf(sv[14], sv[15]);
    float mx = fmaxf(fmaxf(fmaxf(m01, m23), fmaxf(m45, m67)),
                     fmaxf(fmaxf(m89, mab), fmaxf(mcd, mef)));
    mx = fmaxf(mx, __shfl_xor(mx, 16));
    mx = fmaxf(mx, __shfl_xor(mx, 32));
    // defer-max (T13): only rescale when max grew beyond threshold
    if (__any(mx > mstate + DEFER)) {
      float mnew = fmaxf(mstate, mx);
      float alpha = exp2f((mstate - mnew) * CC);  // first tile: underflows to 0
      lstate *= alpha;
      #pragma unroll
      for (int dt = 0; dt < 4; dt++) o_acc[dt] *= alpha;
      mstate = mnew;
    }
    float mc = mstate * CC;
    float p[16];
    float rs = 0.f;
    #pragma unroll
    for (int nt = 0; nt < 4; nt++) {
      float q0 = exp2f(fmaf(sv[nt * 4 + 0], CC, -mc)) * ((const float*)&mmv[nt])[0];
      float q1 = exp2f(fmaf(sv[nt * 4 + 1], CC, -mc)) * ((const float*)&mmv[nt])[1];
      float q2 = exp2f(fmaf(sv[nt * 4 + 2], CC, -mc)) * ((const float*)&mmv[nt])[2];
      float q3 = exp2f(fmaf(sv[nt * 4 + 3], CC, -mc)) * ((const float*)&mmv[nt])[3];
      p[nt * 4 + 0] = q0; p[nt * 4 + 1] = q1; p[nt * 4 + 2] = q2; p[nt * 4 + 3] = q3;
      rs += (q0 + q1) + (q2 + q3);
    }
    rs += __shfl_xor(rs, 16);
    rs += __shfl_xor(rs, 32);
    lstate += rs;

    // ---- pack P^T B-fragments (cvt_pk: 1 op / 2 values) ----
    bf16x4 bq[4];
    #pragma unroll
    for (int s4 = 0; s4 < 4; s4++) {
      uint2 u;
      u.x = cvt_pk_bf16(p[4 * s4 + 0], p[4 * s4 + 1]);
      u.y = cvt_pk_bf16(p[4 * s4 + 2], p[4 * s4 + 3]);
      bq[s4] = __builtin_bit_cast(bf16x4, u);
    }
    // ---- O^T += V^T P^T (vf loaded per-s4 to cap VGPR) ----
    #pragma unroll
    for (int s4 = 0; s4 < 4; s4++) {
      #pragma unroll
      for (int dt = 0; dt < 4; dt++) {
        int row = dt * 16 + r;
        int chunk = (2 * s4 + (g >> 1)) ^ (row & 7);
        bf16x4 vf = *(const bf16x4*)(V_s[cur] + row * 128 + chunk * 16 + (g & 1) * 8);
        o_acc[dt] = mfma16(vf, bq[s4], o_acc[dt]);
      }
    }
    __syncthreads();  // staging (next buf) done + all waves done reading cur buf
  }

  // ---- epilogue: O^T frag -> av[q][h*64 + d], d = 16dt + 4g + rr ----
  float invl = 1.0f / fmaxf(lstate, 1e-30f);
  size_t qrow = tok0 + (size_t)qt * 128 + w * 16 + r;
  unsigned short* base = av + qrow * D_MODEL + h * 64;
  #pragma unroll
  for (int dt = 0; dt < 4; dt++) {
    ushort4 o4 = {f2bf(o_acc[dt][0] * invl), f2bf(o_acc[dt][1] * invl),
                  f2bf(o_acc[dt][2] * invl), f2bf(o_acc[dt][3] * invl)};
    *(ushort4*)(base + dt * 16 + 4 * g) = o4;
  }
}

// ---------------- launch ----------------
extern "C" void kernel_launch(void* const* d_in, const int* in_sizes, int n_in,
                              void* d_out, int out_size, void* d_ws, size_t ws_size,
                              hipStream_t stream) {
  const float* x        = (const float*)d_in[0];
  const void*  mask     = d_in[1];
  const float* ln_in_w  = (const float*)d_in[2];
  const float* ln_in_b  = (const float*)d_in[3];
  const float* qkv_w    = (const float*)d_in[4];
  const float* qkv_b    = (const float*)d_in[5];
  const float* out_w    = (const float*)d_in[6];
  const float* out_b    = (const float*)d_in[7];
  const float* ln_out_w = (const float*)d_in[8];
  const float* ln_out_b = (const float*)d_in[9];
  float* out = (float*)d_out;

  const size_t MB = 1024 * 1024;
  char* ws = (char*)d_ws;
  unsigned short* xn      = (unsigned short*)(ws);             // 8 MB bf16
  unsigned short* qkv     = (unsigned short*)(ws + 8 * MB);    // 24 MB bf16
  unsigned short* Vt      = (unsigned short*)(ws + 32 * MB);   // 8 MB bf16
  unsigned short* av      = (unsigned short*)(ws + 40 * MB);   // 8 MB bf16
  float*          proj    = (float*)(ws + 48 * MB);            // 16 MB f32
  unsigned short* qkv_wT  = (unsigned short*)(ws + 64 * MB);   // 6 MB bf16
  unsigned short* out_wT  = (unsigned short*)(ws + 70 * MB);   // 2 MB bf16
  float*          maskMul = (float*)(ws + 72 * MB);            // 16 KB
  int*            flag    = (int*)(ws + 72 * MB + 16384);

  mask_detect_kernel<<<1, 256, 0, stream>>>((const unsigned char*)mask, flag);
  mask_convert_kernel<<<(NTOK + 255) / 256, 256, 0, stream>>>(mask, flag, maskMul);

  transpose_convert_kernel<<<dim3(3 * D_MODEL / 64, D_MODEL / 64), 256, 0, stream>>>(
      qkv_w, qkv_wT, D_MODEL, 3 * D_MODEL);
  transpose_convert_kernel<<<dim3(D_MODEL / 64, D_MODEL / 64), 256, 0, stream>>>(
      out_w, out_wT, D_MODEL, D_MODEL);

  ln_kernel<true><<<NTOK, 256, 0, stream>>>(x, ln_in_w, ln_in_b, xn);

  gemm_mfma_kernel<unsigned short><<<dim3(3 * D_MODEL / 128, NTOK / 128), 256, 0, stream>>>(
      xn, qkv_wT, qkv_b, qkv, NTOK, 3 * D_MODEL, D_MODEL);

  v_transpose_kernel<<<dim3(SEQ / 64, NH, NBATCH), 256, 0, stream>>>(qkv, Vt);

  attn_mfma_kernel<<<dim3(SEQ / 128, NH, NBATCH), 512, 0, stream>>>(
      qkv, Vt, maskMul, av);

  gemm_mfma_kernel<float><<<dim3(D_MODEL / 128, NTOK / 128), 256, 0, stream>>>(
      av, out_wT, out_b, proj, NTOK, D_MODEL, D_MODEL);

  ln_kernel<false><<<NTOK, 256, 0, stream>>>(proj, ln_out_w, ln_out_b, out);
}

// Round 11
// 178.519 us; speedup vs baseline: 5.4932x; 1.0004x over previous
//
#include <hip/hip_runtime.h>
#include <math.h>

#define D_MODEL 1024
#define SEQ     2048
#define NBATCH  2
#define NTOK    (NBATCH * SEQ)
#define NH      16
#define HD      64

typedef float f32x4 __attribute__((ext_vector_type(4)));
typedef short bf16x8 __attribute__((ext_vector_type(8)));
typedef short bf16x4 __attribute__((ext_vector_type(4)));

__device__ __forceinline__ unsigned short f2bf(float f) {
  unsigned u = __builtin_bit_cast(unsigned, f);
  u += 0x7FFFu + ((u >> 16) & 1u);
  return (unsigned short)(u >> 16);
}

__device__ __forceinline__ unsigned cvt_pk_bf16(float lo, float hi) {
  unsigned d;
  asm("v_cvt_pk_bf16_f32 %0, %1, %2" : "=v"(d) : "v"(lo), "v"(hi));
  return d;
}

__device__ __forceinline__ f32x4 mfma16(bf16x4 a, bf16x4 b, f32x4 c) {
  return __builtin_amdgcn_mfma_f32_16x16x16bf16_1k(a, b, c, 0, 0, 0);
}

__device__ __forceinline__ void gload16(const void* g, void* l) {
  __builtin_amdgcn_global_load_lds(
      (const __attribute__((address_space(1))) void*)g,
      (__attribute__((address_space(3))) void*)l, 16, 0, 0);
}

// ---------------- mask dtype detect / convert ----------------
__global__ void mask_detect_kernel(const unsigned char* __restrict__ m,
                                   int* __restrict__ flag) {
  __shared__ int c1s, c3s;
  if (threadIdx.x == 0) { c1s = 0; c3s = 0; }
  __syncthreads();
  int c1 = 0, c3 = 0;
  for (int i = threadIdx.x; i < NTOK; i += 256) {
    unsigned char v = m[i];
    if (v) {
      if ((i & 3) == 1) c1++;
      if ((i & 3) == 3) c3++;
    }
  }
  if (c1) atomicAdd(&c1s, c1);
  if (c3) atomicAdd(&c3s, c3);
  __syncthreads();
  if (threadIdx.x == 0) *flag = (c1s > 0) ? 1 : ((c3s > 0) ? 2 : 0);
}

__global__ void mask_convert_kernel(const void* __restrict__ m,
                                    const int* __restrict__ flag,
                                    float* __restrict__ maskMul) {
  int i = blockIdx.x * 256 + threadIdx.x;
  if (i >= NTOK) return;
  int f = *flag;
  bool on;
  if (f == 1)      on = ((const unsigned char*)m)[i] != 0;
  else if (f == 2) on = ((const float*)m)[i] != 0.0f;
  else             on = ((const int*)m)[i] != 0;
  maskMul[i] = on ? 1.0f : 0.0f;
}

// ---------------- LayerNorm ----------------
__device__ inline float block_reduce_sum(float v, float* red) {
  #pragma unroll
  for (int s = 1; s < 64; s <<= 1) v += __shfl_xor(v, s);
  int wid = threadIdx.x >> 6, lane = threadIdx.x & 63;
  if (lane == 0) red[wid] = v;
  __syncthreads();
  float t = red[0] + red[1] + red[2] + red[3];
  __syncthreads();
  return t;
}

template <bool BF16OUT>
__global__ __launch_bounds__(256) void ln_kernel(const float* __restrict__ x,
                                                 const float* __restrict__ w,
                                                 const float* __restrict__ b,
                                                 void* __restrict__ yv) {
  __shared__ float red[4];
  int row = blockIdx.x;
  int tid = threadIdx.x;
  float4 v = ((const float4*)(x + (size_t)row * D_MODEL))[tid];
  float s = v.x + v.y + v.z + v.w;
  float tot = block_reduce_sum(s, red);
  float mu = tot * (1.0f / D_MODEL);
  float dx = v.x - mu, dy = v.y - mu, dz = v.z - mu, dw = v.w - mu;
  float sq = dx * dx + dy * dy + dz * dz + dw * dw;
  float tot2 = block_reduce_sum(sq, red);
  float inv = rsqrtf(tot2 * (1.0f / D_MODEL) + 1e-5f);
  float4 wv = ((const float4*)w)[tid];
  float4 bv = ((const float4*)b)[tid];
  float4 o;
  o.x = dx * inv * wv.x + bv.x;
  o.y = dy * inv * wv.y + bv.y;
  o.z = dz * inv * wv.z + bv.z;
  o.w = dw * inv * wv.w + bv.w;
  if constexpr (BF16OUT) {
    ushort4 o4 = {f2bf(o.x), f2bf(o.y), f2bf(o.z), f2bf(o.w)};
    ((ushort4*)((unsigned short*)yv + (size_t)row * D_MODEL))[tid] = o4;
  } else {
    ((float4*)((float*)yv + (size_t)row * D_MODEL))[tid] = o;
  }
}

// ---------------- weight transpose+convert: W[K][N] f32 -> WT[N][K] bf16 ----------------
__global__ __launch_bounds__(256) void transpose_convert_kernel(
    const float* __restrict__ W, unsigned short* __restrict__ WT, int K, int N) {
  __shared__ float t[64][65];
  int k0 = blockIdx.y * 64, n0 = blockIdx.x * 64;
  int tid = threadIdx.x;
  int rr = tid >> 4, cc = (tid & 15) * 4;
  #pragma unroll
  for (int i = 0; i < 4; i++) {
    int rk = i * 16 + rr;
    float4 v = *(const float4*)&W[(size_t)(k0 + rk) * N + n0 + cc];
    t[rk][cc + 0] = v.x; t[rk][cc + 1] = v.y; t[rk][cc + 2] = v.z; t[rk][cc + 3] = v.w;
  }
  __syncthreads();
  #pragma unroll
  for (int i = 0; i < 4; i++) {
    int rn = i * 16 + rr;
    ushort4 o = {f2bf(t[cc + 0][rn]), f2bf(t[cc + 1][rn]),
                 f2bf(t[cc + 2][rn]), f2bf(t[cc + 3][rn])};
    *(ushort4*)&WT[(size_t)(n0 + rn) * K + k0 + cc] = o;
  }
}

// ---------------- V transpose: qkv[tok][2048+h*64+d] bf16 -> Vt[(n*16+h)*64+d][s] ----------------
__global__ __launch_bounds__(256) void v_transpose_kernel(
    const unsigned short* __restrict__ qkv, unsigned short* __restrict__ Vt) {
  __shared__ unsigned short t[64][66];
  int s0 = blockIdx.x * 64;
  int h = blockIdx.y, n = blockIdx.z;
  int tid = threadIdx.x;
  #pragma unroll
  for (int i = 0; i < 2; i++) {
    int ch = i * 256 + tid;
    int sr = ch >> 3, c8 = (ch & 7) * 8;
    const unsigned short* src =
        qkv + (size_t)(n * SEQ + s0 + sr) * 3072 + 2048 + h * 64 + c8;
    uint4 v = *(const uint4*)src;
    unsigned short tmp[8];
    *(uint4*)tmp = v;
    #pragma unroll
    for (int j = 0; j < 8; j++) t[sr][c8 + j] = tmp[j];
  }
  __syncthreads();
  #pragma unroll
  for (int i = 0; i < 2; i++) {
    int ch = i * 256 + tid;
    int d = ch >> 3, s8 = (ch & 7) * 8;
    unsigned short tmp[8];
    #pragma unroll
    for (int j = 0; j < 8; j++) tmp[j] = t[s8 + j][d];
    unsigned short* dst =
        Vt + ((size_t)((n * NH + h) * HD) + d) * SEQ + s0 + s8;
    *(uint4*)dst = *(const uint4*)tmp;
  }
}

// ---------------- bf16 MFMA GEMM (unchanged, verified) ----------------
template <typename OutT>
__global__ __launch_bounds__(256) void gemm_mfma_kernel(
    const unsigned short* __restrict__ A, const unsigned short* __restrict__ BT,
    const float* __restrict__ bias, OutT* __restrict__ C, int M, int N, int K) {
  __shared__ __align__(16) char As[16384];
  __shared__ __align__(16) char Bs[16384];
  int tid = threadIdx.x;
  int lane = tid & 63, w = tid >> 6;
  int r = lane & 15, g = lane >> 4;
  int wm = w >> 1, wn = w & 1;
  int m0 = blockIdx.y * 128, n0 = blockIdx.x * 128;
  f32x4 acc[4][4] = {};

  const char* Ab = (const char*)A;
  const char* Bb = (const char*)BT;
  for (int k0 = 0; k0 < K; k0 += 64) {
    __syncthreads();
    #pragma unroll
    for (int i = 0; i < 4; i++) {
      int chb = i * 256 + w * 64;
      int ch = chb + lane;
      int row = ch >> 3, cb = (ch & 7) ^ (row & 7);
      gload16(Ab + (((size_t)(m0 + row) * K + k0) << 1) + (cb << 4), As + chb * 16);
      gload16(Bb + (((size_t)(n0 + row) * K + k0) << 1) + (cb << 4), Bs + chb * 16);
    }
    __syncthreads();
    #pragma unroll
    for (int s = 0; s < 2; s++) {
      bf16x8 af[4], bfr[4];
      #pragma unroll
      for (int mt = 0; mt < 4; mt++) {
        int arow = wm * 64 + mt * 16 + r;
        int cb = (s * 4 + g) ^ (arow & 7);
        af[mt] = *(const bf16x8*)(As + arow * 128 + cb * 16);
      }
      #pragma unroll
      for (int nt = 0; nt < 4; nt++) {
        int brow = wn * 64 + nt * 16 + r;
        int cb = (s * 4 + g) ^ (brow & 7);
        bfr[nt] = *(const bf16x8*)(Bs + brow * 128 + cb * 16);
      }
      #pragma unroll
      for (int mt = 0; mt < 4; mt++)
        #pragma unroll
        for (int nt = 0; nt < 4; nt++)
          acc[mt][nt] = __builtin_amdgcn_mfma_f32_16x16x32_bf16(
              af[mt], bfr[nt], acc[mt][nt], 0, 0, 0);
    }
  }
  #pragma unroll
  for (int nt = 0; nt < 4; nt++) {
    int col = n0 + wn * 64 + nt * 16 + r;
    float bv = bias[col];
    #pragma unroll
    for (int mt = 0; mt < 4; mt++) {
      #pragma unroll
      for (int rr = 0; rr < 4; rr++) {
        int row = m0 + wm * 64 + mt * 16 + g * 4 + rr;
        float v = acc[mt][nt][rr] + bv;
        if constexpr (sizeof(OutT) == 2) {
          C[(size_t)row * N + col] = (OutT)f2bf(v);
        } else {
          C[(size_t)row * N + col] = v;
        }
      }
    }
  }
}

// ---------------- MFMA flash attention: 8 waves, dbuf K/V, defer-max ----------------
// grid (SEQ/128, NH, NBATCH), 512 thr = 8 waves; wave w owns q-rows [w*16, w*16+16).
// S^T = mfma(K, Q): lane owns the P-row for q = lane&15; kv = 16nt + 4g + rr.
// O^T = mfma16(V^T, P^T): B-frag k = 4g+j == lane's own kv. No P LDS round-trip.
__global__ __launch_bounds__(512, 4) void attn_mfma_kernel(
    const unsigned short* __restrict__ qkv, const unsigned short* __restrict__ Vt,
    const float* __restrict__ maskMulG, unsigned short* __restrict__ av) {
  __shared__ __align__(16) char Q_s[16384];     // [qrow 128][d 64] bf16, chunk-swizzled
  __shared__ __align__(16) char K_s[2][8192];   // dbuf [kv 64][d 64]
  __shared__ __align__(16) char V_s[2][8192];   // dbuf [d 64][kv 64] (V^T)
  int tid = threadIdx.x;
  int lane = tid & 63, w = tid >> 6;
  int r = lane & 15, g = lane >> 4;
  int qt = blockIdx.x, h = blockIdx.y, bn = blockIdx.z;
  size_t tok0 = (size_t)bn * SEQ;

  const char* qb = (const char*)qkv + (((tok0 + qt * 128) * 3072) + h * 64) * 2;
  const char* kb0 = (const char*)qkv + ((tok0 * 3072) + 1024 + h * 64) * 2;
  const char* vb0 = (const char*)Vt + (((size_t)(bn * NH + h) * HD) * SEQ) * 2;

  // Q staging: 1024 chunks over 8 waves
  #pragma unroll
  for (int i = 0; i < 2; i++) {
    int chb = i * 512 + w * 64;
    int ch = chb + lane;
    int row = ch >> 3, cb = (ch & 7) ^ (row & 7);
    gload16(qb + (size_t)row * 6144 + (cb << 4), Q_s + chb * 16);
  }
  // K/V tile staging: 512 chunks each, 1 gload per lane each
  auto stage_kv = [&](int kt, int buf) {
    int chb = w * 64;
    int ch = chb + lane;
    int row = ch >> 3, cb = (ch & 7) ^ (row & 7);
    gload16(kb0 + (size_t)(kt * 64 + row) * 6144 + (cb << 4), K_s[buf] + chb * 16);
    gload16(vb0 + (size_t)row * 4096 + (size_t)kt * 128 + (cb << 4), V_s[buf] + chb * 16);
  };
  stage_kv(0, 0);
  __syncthreads();

  float mstate = -30000.0f;
  float lstate = 0.f;
  f32x4 o_acc[4] = {};  // [dt]: d = 16*dt + 4*g + rr, q = w*16 + r

  const float CC = 0.18033688011112042f;   // 0.125 * log2(e)
  const float DEFER = 44.3614195558365f;   // 8 / CC (raw-score units)

  for (int kt = 0; kt < SEQ / 64; kt++) {
    int cur = kt & 1;
    // mask loads FIRST (so their waitcnt doesn't drain the prefetch gloads)
    float4 mmv[4];
    #pragma unroll
    for (int nt = 0; nt < 4; nt++)
      mmv[nt] = *(const float4*)(maskMulG + tok0 + kt * 64 + nt * 16 + 4 * g);
    // prefetch next K/V tile into the other buffer
    if (kt + 1 < SEQ / 64) stage_kv(kt + 1, cur ^ 1);

    // ---- S^T = K Q^T : sa[nt], row(kv) = nt*16 + 4g+rr, col(q) = r ----
    f32x4 sa[4] = {};
    #pragma unroll
    for (int s = 0; s < 2; s++) {
      int qrow = w * 16 + r;
      int cbq = (s * 4 + g) ^ (qrow & 7);
      bf16x8 qf = *(const bf16x8*)(Q_s + qrow * 128 + cbq * 16);
      #pragma unroll
      for (int nt = 0; nt < 4; nt++) {
        int krow = nt * 16 + r;
        int cb = (s * 4 + g) ^ (krow & 7);
        bf16x8 kf = *(const bf16x8*)(K_s[cur] + krow * 128 + cb * 16);
        sa[nt] = __builtin_amdgcn_mfma_f32_16x16x32_bf16(kf, qf, sa[nt], 0, 0, 0);
      }
    }

    // ---- in-register softmax (lane owns one q-row's 16 kv values) ----
    float sv[16];
    #pragma unroll
    for (int nt = 0; nt < 4; nt++)
      #pragma unroll
      for (int rr = 0; rr < 4; rr++) sv[nt * 4 + rr] = sa[nt][rr];
    // balanced max tree
    float m01 = fmaxf(sv[0], sv[1]),   m23 = fmaxf(sv[2], sv[3]);
    float m45 = fmaxf(sv[4], sv[5]),   m67 = fmaxf(sv[6], sv[7]);
    float m89 = fmaxf(sv[8], sv[9]),   mab = fmaxf(sv[10], sv[11]);
    float mcd = fmaxf(sv[12], sv[13]), mef = fmaxf(sv[14], sv[15]);
    float mx = fmaxf(fmaxf(fmaxf(m01, m23), fmaxf(m45, m67)),
                     fmaxf(fmaxf(m89, mab), fmaxf(mcd, mef)));
    mx = fmaxf(mx, __shfl_xor(mx, 16));
    mx = fmaxf(mx, __shfl_xor(mx, 32));
    // defer-max (T13): only rescale when max grew beyond threshold
    if (__any(mx > mstate + DEFER)) {
      float mnew = fmaxf(mstate, mx);
      float alpha = exp2f((mstate - mnew) * CC);  // first tile: underflows to 0
      lstate *= alpha;
      #pragma unroll
      for (int dt = 0; dt < 4; dt++) o_acc[dt] *= alpha;
      mstate = mnew;
    }
    float mc = mstate * CC;
    float p[16];
    float rs = 0.f;
    #pragma unroll
    for (int nt = 0; nt < 4; nt++) {
      float q0 = exp2f(fmaf(sv[nt * 4 + 0], CC, -mc)) * ((const float*)&mmv[nt])[0];
      float q1 = exp2f(fmaf(sv[nt * 4 + 1], CC, -mc)) * ((const float*)&mmv[nt])[1];
      float q2 = exp2f(fmaf(sv[nt * 4 + 2], CC, -mc)) * ((const float*)&mmv[nt])[2];
      float q3 = exp2f(fmaf(sv[nt * 4 + 3], CC, -mc)) * ((const float*)&mmv[nt])[3];
      p[nt * 4 + 0] = q0; p[nt * 4 + 1] = q1; p[nt * 4 + 2] = q2; p[nt * 4 + 3] = q3;
      rs += (q0 + q1) + (q2 + q3);
    }
    rs += __shfl_xor(rs, 16);
    rs += __shfl_xor(rs, 32);
    lstate += rs;

    // ---- pack P^T B-fragments (cvt_pk: 1 op / 2 values) ----
    bf16x4 bq[4];
    #pragma unroll
    for (int s4 = 0; s4 < 4; s4++) {
      uint2 u;
      u.x = cvt_pk_bf16(p[4 * s4 + 0], p[4 * s4 + 1]);
      u.y = cvt_pk_bf16(p[4 * s4 + 2], p[4 * s4 + 3]);
      bq[s4] = __builtin_bit_cast(bf16x4, u);
    }
    // ---- O^T += V^T P^T (vf loaded per-s4 to cap VGPR) ----
    #pragma unroll
    for (int s4 = 0; s4 < 4; s4++) {
      #pragma unroll
      for (int dt = 0; dt < 4; dt++) {
        int row = dt * 16 + r;
        int chunk = (2 * s4 + (g >> 1)) ^ (row & 7);
        bf16x4 vf = *(const bf16x4*)(V_s[cur] + row * 128 + chunk * 16 + (g & 1) * 8);
        o_acc[dt] = mfma16(vf, bq[s4], o_acc[dt]);
      }
    }
    __syncthreads();  // staging (next buf) done + all waves done reading cur buf
  }

  // ---- epilogue: O^T frag -> av[q][h*64 + d], d = 16dt + 4g + rr ----
  float invl = 1.0f / fmaxf(lstate, 1e-30f);
  size_t qrow = tok0 + (size_t)qt * 128 + w * 16 + r;
  unsigned short* base = av + qrow * D_MODEL + h * 64;
  #pragma unroll
  for (int dt = 0; dt < 4; dt++) {
    ushort4 o4 = {f2bf(o_acc[dt][0] * invl), f2bf(o_acc[dt][1] * invl),
                  f2bf(o_acc[dt][2] * invl), f2bf(o_acc[dt][3] * invl)};
    *(ushort4*)(base + dt * 16 + 4 * g) = o4;
  }
}

// ---------------- launch ----------------
extern "C" void kernel_launch(void* const* d_in, const int* in_sizes, int n_in,
                              void* d_out, int out_size, void* d_ws, size_t ws_size,
                              hipStream_t stream) {
  const float* x        = (const float*)d_in[0];
  const void*  mask     = d_in[1];
  const float* ln_in_w  = (const float*)d_in[2];
  const float* ln_in_b  = (const float*)d_in[3];
  const float* qkv_w    = (const float*)d_in[4];
  const float* qkv_b    = (const float*)d_in[5];
  const float* out_w    = (const float*)d_in[6];
  const float* out_b    = (const float*)d_in[7];
  const float* ln_out_w = (const float*)d_in[8];
  const float* ln_out_b = (const float*)d_in[9];
  float* out = (float*)d_out;

  const size_t MB = 1024 * 1024;
  char* ws = (char*)d_ws;
  unsigned short* xn      = (unsigned short*)(ws);             // 8 MB bf16
  unsigned short* qkv     = (unsigned short*)(ws + 8 * MB);    // 24 MB bf16
  unsigned short* Vt      = (unsigned short*)(ws + 32 * MB);   // 8 MB bf16
  unsigned short* av      = (unsigned short*)(ws + 40 * MB);   // 8 MB bf16
  float*          proj    = (float*)(ws + 48 * MB);            // 16 MB f32
  unsigned short* qkv_wT  = (unsigned short*)(ws + 64 * MB);   // 6 MB bf16
  unsigned short* out_wT  = (unsigned short*)(ws + 70 * MB);   // 2 MB bf16
  float*          maskMul = (float*)(ws + 72 * MB);            // 16 KB
  int*            flag    = (int*)(ws + 72 * MB + 16384);

  mask_detect_kernel<<<1, 256, 0, stream>>>((const unsigned char*)mask, flag);
  mask_convert_kernel<<<(NTOK + 255) / 256, 256, 0, stream>>>(mask, flag, maskMul);

  transpose_convert_kernel<<<dim3(3 * D_MODEL / 64, D_MODEL / 64), 256, 0, stream>>>(
      qkv_w, qkv_wT, D_MODEL, 3 * D_MODEL);
  transpose_convert_kernel<<<dim3(D_MODEL / 64, D_MODEL / 64), 256, 0, stream>>>(
      out_w, out_wT, D_MODEL, D_MODEL);

  ln_kernel<true><<<NTOK, 256, 0, stream>>>(x, ln_in_w, ln_in_b, xn);

  gemm_mfma_kernel<unsigned short><<<dim3(3 * D_MODEL / 128, NTOK / 128), 256, 0, stream>>>(
      xn, qkv_wT, qkv_b, qkv, NTOK, 3 * D_MODEL, D_MODEL);

  v_transpose_kernel<<<dim3(SEQ / 64, NH, NBATCH), 256, 0, stream>>>(qkv, Vt);

  attn_mfma_kernel<<<dim3(SEQ / 128, NH, NBATCH), 512, 0, stream>>>(
      qkv, Vt, maskMul, av);

  gemm_mfma_kernel<float><<<dim3(D_MODEL / 128, NTOK / 128), 256, 0, stream>>>(
      av, out_wT, out_b, proj, NTOK, D_MODEL, D_MODEL);

  ln_kernel<false><<<NTOK, 256, 0, stream>>>(proj, ln_out_w, ln_out_b, out);
}

// Round 12
// 173.016 us; speedup vs baseline: 5.6679x; 1.0318x over previous
//
#include <hip/hip_runtime.h>
#include <math.h>

#define D_MODEL 1024
#define SEQ     2048
#define NBATCH  2
#define NTOK    (NBATCH * SEQ)
#define NH      16
#define HD      64

typedef float f32x4 __attribute__((ext_vector_type(4)));
typedef short bf16x8 __attribute__((ext_vector_type(8)));
typedef short bf16x4 __attribute__((ext_vector_type(4)));

__device__ __forceinline__ unsigned short f2bf(float f) {
  unsigned u = __builtin_bit_cast(unsigned, f);
  u += 0x7FFFu + ((u >> 16) & 1u);
  return (unsigned short)(u >> 16);
}

__device__ __forceinline__ float bf2f(unsigned short h) {
  return __builtin_bit_cast(float, (unsigned)h << 16);
}

__device__ __forceinline__ unsigned cvt_pk_bf16(float lo, float hi) {
  unsigned d;
  asm("v_cvt_pk_bf16_f32 %0, %1, %2" : "=v"(d) : "v"(lo), "v"(hi));
  return d;
}

__device__ __forceinline__ f32x4 mfma16(bf16x4 a, bf16x4 b, f32x4 c) {
  return __builtin_amdgcn_mfma_f32_16x16x16bf16_1k(a, b, c, 0, 0, 0);
}

__device__ __forceinline__ void gload16(const void* g, void* l) {
  __builtin_amdgcn_global_load_lds(
      (const __attribute__((address_space(1))) void*)g,
      (__attribute__((address_space(3))) void*)l, 16, 0, 0);
}

// ---------------- mask convert with per-block self-detection ----------------
// Detection scan (first NTOK bytes, L2-hot) is redundantly repeated per block;
// removes the separate detect kernel + flag round-trip.
__global__ __launch_bounds__(256) void mask_convert_kernel(
    const void* __restrict__ m, float* __restrict__ maskMul) {
  __shared__ int c1s, c3s;
  if (threadIdx.x == 0) { c1s = 0; c3s = 0; }
  __syncthreads();
  const unsigned char* mb = (const unsigned char*)m;
  int c1 = 0, c3 = 0;
  for (int i = threadIdx.x; i < NTOK; i += 256) {
    unsigned char v = mb[i];
    if (v) {
      if ((i & 3) == 1) c1++;
      if ((i & 3) == 3) c3++;
    }
  }
  if (c1) atomicAdd(&c1s, c1);
  if (c3) atomicAdd(&c3s, c3);
  __syncthreads();
  int f = (c1s > 0) ? 1 : ((c3s > 0) ? 2 : 0);
  int i = blockIdx.x * 256 + threadIdx.x;
  if (i >= NTOK) return;
  bool on;
  if (f == 1)      on = mb[i] != 0;
  else if (f == 2) on = ((const float*)m)[i] != 0.0f;
  else             on = ((const int*)m)[i] != 0;
  maskMul[i] = on ? 1.0f : 0.0f;
}

// ---------------- LayerNorm (templated in/out dtype) ----------------
__device__ inline float block_reduce_sum(float v, float* red) {
  #pragma unroll
  for (int s = 1; s < 64; s <<= 1) v += __shfl_xor(v, s);
  int wid = threadIdx.x >> 6, lane = threadIdx.x & 63;
  if (lane == 0) red[wid] = v;
  __syncthreads();
  float t = red[0] + red[1] + red[2] + red[3];
  __syncthreads();
  return t;
}

template <bool BF16IN, bool BF16OUT>
__global__ __launch_bounds__(256) void ln_kernel(const void* __restrict__ xv,
                                                 const float* __restrict__ w,
                                                 const float* __restrict__ b,
                                                 void* __restrict__ yv) {
  __shared__ float red[4];
  int row = blockIdx.x;
  int tid = threadIdx.x;
  float4 v;
  if constexpr (BF16IN) {
    ushort4 u = ((const ushort4*)((const unsigned short*)xv + (size_t)row * D_MODEL))[tid];
    v.x = bf2f(u.x); v.y = bf2f(u.y); v.z = bf2f(u.z); v.w = bf2f(u.w);
  } else {
    v = ((const float4*)((const float*)xv + (size_t)row * D_MODEL))[tid];
  }
  float s = v.x + v.y + v.z + v.w;
  float tot = block_reduce_sum(s, red);
  float mu = tot * (1.0f / D_MODEL);
  float dx = v.x - mu, dy = v.y - mu, dz = v.z - mu, dw = v.w - mu;
  float sq = dx * dx + dy * dy + dz * dz + dw * dw;
  float tot2 = block_reduce_sum(sq, red);
  float inv = rsqrtf(tot2 * (1.0f / D_MODEL) + 1e-5f);
  float4 wv = ((const float4*)w)[tid];
  float4 bv = ((const float4*)b)[tid];
  float4 o;
  o.x = dx * inv * wv.x + bv.x;
  o.y = dy * inv * wv.y + bv.y;
  o.z = dz * inv * wv.z + bv.z;
  o.w = dw * inv * wv.w + bv.w;
  if constexpr (BF16OUT) {
    ushort4 o4 = {f2bf(o.x), f2bf(o.y), f2bf(o.z), f2bf(o.w)};
    ((ushort4*)((unsigned short*)yv + (size_t)row * D_MODEL))[tid] = o4;
  } else {
    ((float4*)((float*)yv + (size_t)row * D_MODEL))[tid] = o;
  }
}

// ---------------- merged weight transpose+convert (both weights, K=1024) ----------------
// grid.x in [0,64): 0..47 -> qkv_w (N=3072), 48..63 -> out_w (N=1024)
__global__ __launch_bounds__(256) void transpose_convert2_kernel(
    const float* __restrict__ Wq, unsigned short* __restrict__ WTq,
    const float* __restrict__ Wo, unsigned short* __restrict__ WTo) {
  __shared__ float t[64][65];
  int bx = blockIdx.x;
  const float* W;
  unsigned short* WT;
  int N, n0;
  if (bx < 48) { W = Wq; WT = WTq; N = 3072; n0 = bx * 64; }
  else         { W = Wo; WT = WTo; N = 1024; n0 = (bx - 48) * 64; }
  const int K = 1024;
  int k0 = blockIdx.y * 64;
  int tid = threadIdx.x;
  int rr = tid >> 4, cc = (tid & 15) * 4;
  #pragma unroll
  for (int i = 0; i < 4; i++) {
    int rk = i * 16 + rr;
    float4 v = *(const float4*)&W[(size_t)(k0 + rk) * N + n0 + cc];
    t[rk][cc + 0] = v.x; t[rk][cc + 1] = v.y; t[rk][cc + 2] = v.z; t[rk][cc + 3] = v.w;
  }
  __syncthreads();
  #pragma unroll
  for (int i = 0; i < 4; i++) {
    int rn = i * 16 + rr;
    ushort4 o = {f2bf(t[cc + 0][rn]), f2bf(t[cc + 1][rn]),
                 f2bf(t[cc + 2][rn]), f2bf(t[cc + 3][rn])};
    *(ushort4*)&WT[(size_t)(n0 + rn) * K + k0 + cc] = o;
  }
}

// ---------------- V transpose: qkv[tok][2048+h*64+d] bf16 -> Vt[(n*16+h)*64+d][s] ----------------
__global__ __launch_bounds__(256) void v_transpose_kernel(
    const unsigned short* __restrict__ qkv, unsigned short* __restrict__ Vt) {
  __shared__ unsigned short t[64][66];
  int s0 = blockIdx.x * 64;
  int h = blockIdx.y, n = blockIdx.z;
  int tid = threadIdx.x;
  #pragma unroll
  for (int i = 0; i < 2; i++) {
    int ch = i * 256 + tid;
    int sr = ch >> 3, c8 = (ch & 7) * 8;
    const unsigned short* src =
        qkv + (size_t)(n * SEQ + s0 + sr) * 3072 + 2048 + h * 64 + c8;
    uint4 v = *(const uint4*)src;
    unsigned short tmp[8];
    *(uint4*)tmp = v;
    #pragma unroll
    for (int j = 0; j < 8; j++) t[sr][c8 + j] = tmp[j];
  }
  __syncthreads();
  #pragma unroll
  for (int i = 0; i < 2; i++) {
    int ch = i * 256 + tid;
    int d = ch >> 3, s8 = (ch & 7) * 8;
    unsigned short tmp[8];
    #pragma unroll
    for (int j = 0; j < 8; j++) tmp[j] = t[s8 + j][d];
    unsigned short* dst =
        Vt + ((size_t)((n * NH + h) * HD) + d) * SEQ + s0 + s8;
    *(uint4*)dst = *(const uint4*)tmp;
  }
}

// ---------------- bf16 MFMA GEMM (unchanged, verified) ----------------
template <typename OutT>
__global__ __launch_bounds__(256) void gemm_mfma_kernel(
    const unsigned short* __restrict__ A, const unsigned short* __restrict__ BT,
    const float* __restrict__ bias, OutT* __restrict__ C, int M, int N, int K) {
  __shared__ __align__(16) char As[16384];
  __shared__ __align__(16) char Bs[16384];
  int tid = threadIdx.x;
  int lane = tid & 63, w = tid >> 6;
  int r = lane & 15, g = lane >> 4;
  int wm = w >> 1, wn = w & 1;
  int m0 = blockIdx.y * 128, n0 = blockIdx.x * 128;
  f32x4 acc[4][4] = {};

  const char* Ab = (const char*)A;
  const char* Bb = (const char*)BT;
  for (int k0 = 0; k0 < K; k0 += 64) {
    __syncthreads();
    #pragma unroll
    for (int i = 0; i < 4; i++) {
      int chb = i * 256 + w * 64;
      int ch = chb + lane;
      int row = ch >> 3, cb = (ch & 7) ^ (row & 7);
      gload16(Ab + (((size_t)(m0 + row) * K + k0) << 1) + (cb << 4), As + chb * 16);
      gload16(Bb + (((size_t)(n0 + row) * K + k0) << 1) + (cb << 4), Bs + chb * 16);
    }
    __syncthreads();
    #pragma unroll
    for (int s = 0; s < 2; s++) {
      bf16x8 af[4], bfr[4];
      #pragma unroll
      for (int mt = 0; mt < 4; mt++) {
        int arow = wm * 64 + mt * 16 + r;
        int cb = (s * 4 + g) ^ (arow & 7);
        af[mt] = *(const bf16x8*)(As + arow * 128 + cb * 16);
      }
      #pragma unroll
      for (int nt = 0; nt < 4; nt++) {
        int brow = wn * 64 + nt * 16 + r;
        int cb = (s * 4 + g) ^ (brow & 7);
        bfr[nt] = *(const bf16x8*)(Bs + brow * 128 + cb * 16);
      }
      #pragma unroll
      for (int mt = 0; mt < 4; mt++)
        #pragma unroll
        for (int nt = 0; nt < 4; nt++)
          acc[mt][nt] = __builtin_amdgcn_mfma_f32_16x16x32_bf16(
              af[mt], bfr[nt], acc[mt][nt], 0, 0, 0);
    }
  }
  #pragma unroll
  for (int nt = 0; nt < 4; nt++) {
    int col = n0 + wn * 64 + nt * 16 + r;
    float bv = bias[col];
    #pragma unroll
    for (int mt = 0; mt < 4; mt++) {
      #pragma unroll
      for (int rr = 0; rr < 4; rr++) {
        int row = m0 + wm * 64 + mt * 16 + g * 4 + rr;
        float v = acc[mt][nt][rr] + bv;
        if constexpr (sizeof(OutT) == 2) {
          C[(size_t)row * N + col] = (OutT)f2bf(v);
        } else {
          C[(size_t)row * N + col] = v;
        }
      }
    }
  }
}

// ---------------- MFMA flash attention: 8 waves, dbuf K/V, defer-max ----------------
// FROZEN: byte-identical to the round-7/round-11 green kernel. Do not edit.
// grid (SEQ/128, NH, NBATCH), 512 thr = 8 waves; wave w owns q-rows [w*16, w*16+16).
// S^T = mfma(K, Q): lane owns the P-row for q = lane&15; kv = 16nt + 4g + rr.
// O^T = mfma16(V^T, P^T): B-frag k = 4g+j == lane's own kv. No P LDS round-trip.
__global__ __launch_bounds__(512, 4) void attn_mfma_kernel(
    const unsigned short* __restrict__ qkv, const unsigned short* __restrict__ Vt,
    const float* __restrict__ maskMulG, unsigned short* __restrict__ av) {
  __shared__ __align__(16) char Q_s[16384];     // [qrow 128][d 64] bf16, chunk-swizzled
  __shared__ __align__(16) char K_s[2][8192];   // dbuf [kv 64][d 64]
  __shared__ __align__(16) char V_s[2][8192];   // dbuf [d 64][kv 64] (V^T)
  int tid = threadIdx.x;
  int lane = tid & 63, w = tid >> 6;
  int r = lane & 15, g = lane >> 4;
  int qt = blockIdx.x, h = blockIdx.y, bn = blockIdx.z;
  size_t tok0 = (size_t)bn * SEQ;

  const char* qb = (const char*)qkv + (((tok0 + qt * 128) * 3072) + h * 64) * 2;
  const char* kb0 = (const char*)qkv + ((tok0 * 3072) + 1024 + h * 64) * 2;
  const char* vb0 = (const char*)Vt + (((size_t)(bn * NH + h) * HD) * SEQ) * 2;

  // Q staging: 1024 chunks over 8 waves
  #pragma unroll
  for (int i = 0; i < 2; i++) {
    int chb = i * 512 + w * 64;
    int ch = chb + lane;
    int row = ch >> 3, cb = (ch & 7) ^ (row & 7);
    gload16(qb + (size_t)row * 6144 + (cb << 4), Q_s + chb * 16);
  }
  // K/V tile staging: 512 chunks each, 1 gload per lane each
  auto stage_kv = [&](int kt, int buf) {
    int chb = w * 64;
    int ch = chb + lane;
    int row = ch >> 3, cb = (ch & 7) ^ (row & 7);
    gload16(kb0 + (size_t)(kt * 64 + row) * 6144 + (cb << 4), K_s[buf] + chb * 16);
    gload16(vb0 + (size_t)row * 4096 + (size_t)kt * 128 + (cb << 4), V_s[buf] + chb * 16);
  };
  stage_kv(0, 0);
  __syncthreads();

  float mstate = -30000.0f;
  float lstate = 0.f;
  f32x4 o_acc[4] = {};  // [dt]: d = 16*dt + 4*g + rr, q = w*16 + r

  const float CC = 0.18033688011112042f;   // 0.125 * log2(e)
  const float DEFER = 44.3614195558365f;   // 8 / CC (raw-score units)

  for (int kt = 0; kt < SEQ / 64; kt++) {
    int cur = kt & 1;
    // mask loads FIRST (so their waitcnt doesn't drain the prefetch gloads)
    float4 mmv[4];
    #pragma unroll
    for (int nt = 0; nt < 4; nt++)
      mmv[nt] = *(const float4*)(maskMulG + tok0 + kt * 64 + nt * 16 + 4 * g);
    // prefetch next K/V tile into the other buffer
    if (kt + 1 < SEQ / 64) stage_kv(kt + 1, cur ^ 1);

    // ---- S^T = K Q^T : sa[nt], row(kv) = nt*16 + 4g+rr, col(q) = r ----
    f32x4 sa[4] = {};
    #pragma unroll
    for (int s = 0; s < 2; s++) {
      int qrow = w * 16 + r;
      int cbq = (s * 4 + g) ^ (qrow & 7);
      bf16x8 qf = *(const bf16x8*)(Q_s + qrow * 128 + cbq * 16);
      #pragma unroll
      for (int nt = 0; nt < 4; nt++) {
        int krow = nt * 16 + r;
        int cb = (s * 4 + g) ^ (krow & 7);
        bf16x8 kf = *(const bf16x8*)(K_s[cur] + krow * 128 + cb * 16);
        sa[nt] = __builtin_amdgcn_mfma_f32_16x16x32_bf16(kf, qf, sa[nt], 0, 0, 0);
      }
    }

    // ---- in-register softmax (lane owns one q-row's 16 kv values) ----
    float sv[16];
    #pragma unroll
    for (int nt = 0; nt < 4; nt++)
      #pragma unroll
      for (int rr = 0; rr < 4; rr++) sv[nt * 4 + rr] = sa[nt][rr];
    // balanced max tree
    float m01 = fmaxf(sv[0], sv[1]),   m23 = fmaxf(sv[2], sv[3]);
    float m45 = fmaxf(sv[4], sv[5]),   m67 = fmaxf(sv[6], sv[7]);
    float m89 = fmaxf(sv[8], sv[9]),   mab = fmaxf(sv[10], sv[11]);
    float mcd = fmaxf(sv[12], sv[13]), mef = fmaxf(sv[14], sv[15]);
    float mx = fmaxf(fmaxf(fmaxf(m01, m23), fmaxf(m45, m67)),
                     fmaxf(fmaxf(m89, mab), fmaxf(mcd, mef)));
    mx = fmaxf(mx, __shfl_xor(mx, 16));
    mx = fmaxf(mx, __shfl_xor(mx, 32));
    // defer-max (T13): only rescale when max grew beyond threshold
    if (__any(mx > mstate + DEFER)) {
      float mnew = fmaxf(mstate, mx);
      float alpha = exp2f((mstate - mnew) * CC);  // first tile: underflows to 0
      lstate *= alpha;
      #pragma unroll
      for (int dt = 0; dt < 4; dt++) o_acc[dt] *= alpha;
      mstate = mnew;
    }
    float mc = mstate * CC;
    float p[16];
    float rs = 0.f;
    #pragma unroll
    for (int nt = 0; nt < 4; nt++) {
      float q0 = exp2f(fmaf(sv[nt * 4 + 0], CC, -mc)) * ((const float*)&mmv[nt])[0];
      float q1 = exp2f(fmaf(sv[nt * 4 + 1], CC, -mc)) * ((const float*)&mmv[nt])[1];
      float q2 = exp2f(fmaf(sv[nt * 4 + 2], CC, -mc)) * ((const float*)&mmv[nt])[2];
      float q3 = exp2f(fmaf(sv[nt * 4 + 3], CC, -mc)) * ((const float*)&mmv[nt])[3];
      p[nt * 4 + 0] = q0; p[nt * 4 + 1] = q1; p[nt * 4 + 2] = q2; p[nt * 4 + 3] = q3;
      rs += (q0 + q1) + (q2 + q3);
    }
    rs += __shfl_xor(rs, 16);
    rs += __shfl_xor(rs, 32);
    lstate += rs;

    // ---- pack P^T B-fragments (cvt_pk: 1 op / 2 values) ----
    bf16x4 bq[4];
    #pragma unroll
    for (int s4 = 0; s4 < 4; s4++) {
      uint2 u;
      u.x = cvt_pk_bf16(p[4 * s4 + 0], p[4 * s4 + 1]);
      u.y = cvt_pk_bf16(p[4 * s4 + 2], p[4 * s4 + 3]);
      bq[s4] = __builtin_bit_cast(bf16x4, u);
    }
    // ---- O^T += V^T P^T (vf loaded per-s4 to cap VGPR) ----
    #pragma unroll
    for (int s4 = 0; s4 < 4; s4++) {
      #pragma unroll
      for (int dt = 0; dt < 4; dt++) {
        int row = dt * 16 + r;
        int chunk = (2 * s4 + (g >> 1)) ^ (row & 7);
        bf16x4 vf = *(const bf16x4*)(V_s[cur] + row * 128 + chunk * 16 + (g & 1) * 8);
        o_acc[dt] = mfma16(vf, bq[s4], o_acc[dt]);
      }
    }
    __syncthreads();  // staging (next buf) done + all waves done reading cur buf
  }

  // ---- epilogue: O^T frag -> av[q][h*64 + d], d = 16dt + 4g + rr ----
  float invl = 1.0f / fmaxf(lstate, 1e-30f);
  size_t qrow = tok0 + (size_t)qt * 128 + w * 16 + r;
  unsigned short* base = av + qrow * D_MODEL + h * 64;
  #pragma unroll
  for (int dt = 0; dt < 4; dt++) {
    ushort4 o4 = {f2bf(o_acc[dt][0] * invl), f2bf(o_acc[dt][1] * invl),
                  f2bf(o_acc[dt][2] * invl), f2bf(o_acc[dt][3] * invl)};
    *(ushort4*)(base + dt * 16 + 4 * g) = o4;
  }
}

// ---------------- launch ----------------
extern "C" void kernel_launch(void* const* d_in, const int* in_sizes, int n_in,
                              void* d_out, int out_size, void* d_ws, size_t ws_size,
                              hipStream_t stream) {
  const float* x        = (const float*)d_in[0];
  const void*  mask     = d_in[1];
  const float* ln_in_w  = (const float*)d_in[2];
  const float* ln_in_b  = (const float*)d_in[3];
  const float* qkv_w    = (const float*)d_in[4];
  const float* qkv_b    = (const float*)d_in[5];
  const float* out_w    = (const float*)d_in[6];
  const float* out_b    = (const float*)d_in[7];
  const float* ln_out_w = (const float*)d_in[8];
  const float* ln_out_b = (const float*)d_in[9];
  float* out = (float*)d_out;

  const size_t MB = 1024 * 1024;
  char* ws = (char*)d_ws;
  unsigned short* xn      = (unsigned short*)(ws);             // 8 MB bf16
  unsigned short* qkv     = (unsigned short*)(ws + 8 * MB);    // 24 MB bf16
  unsigned short* Vt      = (unsigned short*)(ws + 32 * MB);   // 8 MB bf16
  unsigned short* av      = (unsigned short*)(ws + 40 * MB);   // 8 MB bf16
  unsigned short* proj    = (unsigned short*)(ws + 48 * MB);   // 8 MB bf16 (was f32)
  unsigned short* qkv_wT  = (unsigned short*)(ws + 64 * MB);   // 6 MB bf16
  unsigned short* out_wT  = (unsigned short*)(ws + 70 * MB);   // 2 MB bf16
  float*          maskMul = (float*)(ws + 72 * MB);            // 16 KB

  mask_convert_kernel<<<(NTOK + 255) / 256, 256, 0, stream>>>(mask, maskMul);

  transpose_convert2_kernel<<<dim3(64, 16), 256, 0, stream>>>(
      qkv_w, qkv_wT, out_w, out_wT);

  ln_kernel<false, true><<<NTOK, 256, 0, stream>>>(x, ln_in_w, ln_in_b, xn);

  gemm_mfma_kernel<unsigned short><<<dim3(3 * D_MODEL / 128, NTOK / 128), 256, 0, stream>>>(
      xn, qkv_wT, qkv_b, qkv, NTOK, 3 * D_MODEL, D_MODEL);

  v_transpose_kernel<<<dim3(SEQ / 64, NH, NBATCH), 256, 0, stream>>>(qkv, Vt);

  attn_mfma_kernel<<<dim3(SEQ / 128, NH, NBATCH), 512, 0, stream>>>(
      qkv, Vt, maskMul, av);

  gemm_mfma_kernel<unsigned short><<<dim3(D_MODEL / 128, NTOK / 128), 256, 0, stream>>>(
      av, out_wT, out_b, proj, NTOK, D_MODEL, D_MODEL);

  ln_kernel<true, false><<<NTOK, 256, 0, stream>>>(proj, ln_out_w, ln_out_b, out);
}

// Round 13
// 153.454 us; speedup vs baseline: 6.3905x; 1.1275x over previous
//
#include <hip/hip_runtime.h>
#include <math.h>

#define D_MODEL 1024
#define SEQ     2048
#define NBATCH  2
#define NTOK    (NBATCH * SEQ)
#define NH      16
#define HD      64

typedef float f32x4 __attribute__((ext_vector_type(4)));
typedef short bf16x8 __attribute__((ext_vector_type(8)));
typedef short bf16x4 __attribute__((ext_vector_type(4)));

__device__ __forceinline__ unsigned short f2bf(float f) {
  unsigned u = __builtin_bit_cast(unsigned, f);
  u += 0x7FFFu + ((u >> 16) & 1u);
  return (unsigned short)(u >> 16);
}

__device__ __forceinline__ float bf2f(unsigned short h) {
  return __builtin_bit_cast(float, (unsigned)h << 16);
}

__device__ __forceinline__ unsigned cvt_pk_bf16(float lo, float hi) {
  unsigned d;
  asm("v_cvt_pk_bf16_f32 %0, %1, %2" : "=v"(d) : "v"(lo), "v"(hi));
  return d;
}

__device__ __forceinline__ f32x4 mfma16(bf16x4 a, bf16x4 b, f32x4 c) {
  return __builtin_amdgcn_mfma_f32_16x16x16bf16_1k(a, b, c, 0, 0, 0);
}

__device__ __forceinline__ void gload16(const void* g, void* l) {
  __builtin_amdgcn_global_load_lds(
      (const __attribute__((address_space(1))) void*)g,
      (__attribute__((address_space(3))) void*)l, 16, 0, 0);
}

// ---------------- LayerNorm row helper (templated in/out dtype) ----------------
__device__ __forceinline__ float block_reduce_sum(float v, float* red) {
  #pragma unroll
  for (int s = 1; s < 64; s <<= 1) v += __shfl_xor(v, s);
  int wid = threadIdx.x >> 6, lane = threadIdx.x & 63;
  if (lane == 0) red[wid] = v;
  __syncthreads();
  float t = red[0] + red[1] + red[2] + red[3];
  __syncthreads();
  return t;
}

template <bool BF16IN, bool BF16OUT>
__device__ __forceinline__ void ln_row(const void* __restrict__ xv,
                                       const float* __restrict__ w,
                                       const float* __restrict__ b,
                                       void* __restrict__ yv, int row, float* red) {
  int tid = threadIdx.x;
  float4 v;
  if constexpr (BF16IN) {
    ushort4 u = ((const ushort4*)((const unsigned short*)xv + (size_t)row * D_MODEL))[tid];
    v.x = bf2f(u.x); v.y = bf2f(u.y); v.z = bf2f(u.z); v.w = bf2f(u.w);
  } else {
    v = ((const float4*)((const float*)xv + (size_t)row * D_MODEL))[tid];
  }
  float s = v.x + v.y + v.z + v.w;
  float tot = block_reduce_sum(s, red);
  float mu = tot * (1.0f / D_MODEL);
  float dx = v.x - mu, dy = v.y - mu, dz = v.z - mu, dw = v.w - mu;
  float sq = dx * dx + dy * dy + dz * dz + dw * dw;
  float tot2 = block_reduce_sum(sq, red);
  float inv = rsqrtf(tot2 * (1.0f / D_MODEL) + 1e-5f);
  float4 wv = ((const float4*)w)[tid];
  float4 bv = ((const float4*)b)[tid];
  float4 o;
  o.x = dx * inv * wv.x + bv.x;
  o.y = dy * inv * wv.y + bv.y;
  o.z = dz * inv * wv.z + bv.z;
  o.w = dw * inv * wv.w + bv.w;
  if constexpr (BF16OUT) {
    ushort4 o4 = {f2bf(o.x), f2bf(o.y), f2bf(o.z), f2bf(o.w)};
    ((ushort4*)((unsigned short*)yv + (size_t)row * D_MODEL))[tid] = o4;
  } else {
    ((float4*)((float*)yv + (size_t)row * D_MODEL))[tid] = o;
  }
}

// ---------------- fused pre-kernel: mask convert | weight transpose | LN1 ----------------
// blocks [0,16): mask dtype-detect + convert; [16,1040): weight transpose+convert
// (48x16 qkv_w tiles then 16x16 out_w tiles); [1040,5136): LN1 rows.
__global__ __launch_bounds__(256) void pre_kernel(
    const void* __restrict__ mask, float* __restrict__ maskMul,
    const float* __restrict__ Wq, unsigned short* __restrict__ WTq,
    const float* __restrict__ Wo, unsigned short* __restrict__ WTo,
    const float* __restrict__ x, const float* __restrict__ ln_in_w,
    const float* __restrict__ ln_in_b, unsigned short* __restrict__ xn) {
  __shared__ float t[64][65];
  __shared__ float red[4];
  __shared__ int c1s, c3s;
  int blk = blockIdx.x;
  int tid = threadIdx.x;

  if (blk < 16) {
    // ---- mask role (detection scan repeated per block; L2-hot) ----
    if (tid == 0) { c1s = 0; c3s = 0; }
    __syncthreads();
    const unsigned char* mb = (const unsigned char*)mask;
    int c1 = 0, c3 = 0;
    for (int i = tid; i < NTOK; i += 256) {
      unsigned char v = mb[i];
      if (v) {
        if ((i & 3) == 1) c1++;
        if ((i & 3) == 3) c3++;
      }
    }
    if (c1) atomicAdd(&c1s, c1);
    if (c3) atomicAdd(&c3s, c3);
    __syncthreads();
    int f = (c1s > 0) ? 1 : ((c3s > 0) ? 2 : 0);
    int i = blk * 256 + tid;
    bool on;
    if (f == 1)      on = mb[i] != 0;
    else if (f == 2) on = ((const float*)mask)[i] != 0.0f;
    else             on = ((const int*)mask)[i] != 0;
    maskMul[i] = on ? 1.0f : 0.0f;
  } else if (blk < 16 + 1024) {
    // ---- weight transpose role: W[K][N] f32 -> WT[N][K] bf16 (K=1024) ----
    int idx = blk - 16;
    int bxx = idx & 63, byy = idx >> 6;
    const float* W;
    unsigned short* WT;
    int N, n0;
    if (bxx < 48) { W = Wq; WT = WTq; N = 3072; n0 = bxx * 64; }
    else          { W = Wo; WT = WTo; N = 1024; n0 = (bxx - 48) * 64; }
    const int K = 1024;
    int k0 = byy * 64;
    int rr = tid >> 4, cc = (tid & 15) * 4;
    #pragma unroll
    for (int i = 0; i < 4; i++) {
      int rk = i * 16 + rr;
      float4 v = *(const float4*)&W[(size_t)(k0 + rk) * N + n0 + cc];
      t[rk][cc + 0] = v.x; t[rk][cc + 1] = v.y; t[rk][cc + 2] = v.z; t[rk][cc + 3] = v.w;
    }
    __syncthreads();
    #pragma unroll
    for (int i = 0; i < 4; i++) {
      int rn = i * 16 + rr;
      ushort4 o = {f2bf(t[cc + 0][rn]), f2bf(t[cc + 1][rn]),
                   f2bf(t[cc + 2][rn]), f2bf(t[cc + 3][rn])};
      *(ushort4*)&WT[(size_t)(n0 + rn) * K + k0 + cc] = o;
    }
  } else {
    // ---- LN1 role: f32 in, bf16 out ----
    int row = blk - 1040;
    ln_row<false, true>(x, ln_in_w, ln_in_b, xn, row, red);
  }
}

// ---------------- LN2 (bf16 in, f32 out) ----------------
__global__ __launch_bounds__(256) void ln2_kernel(const unsigned short* __restrict__ xv,
                                                  const float* __restrict__ w,
                                                  const float* __restrict__ b,
                                                  float* __restrict__ yv) {
  __shared__ float red[4];
  ln_row<true, false>(xv, w, b, yv, blockIdx.x, red);
}

// ---------------- bf16 MFMA GEMM; FUSEV: cols>=2048 write transposed to Vt ----------------
template <typename OutT, bool FUSEV>
__global__ __launch_bounds__(256) void gemm_mfma_kernel(
    const unsigned short* __restrict__ A, const unsigned short* __restrict__ BT,
    const float* __restrict__ bias, OutT* __restrict__ C, int M, int N, int K,
    unsigned short* __restrict__ VtOut) {
  __shared__ __align__(16) char As[16384];
  __shared__ __align__(16) char Bs[16384];
  int tid = threadIdx.x;
  int lane = tid & 63, w = tid >> 6;
  int r = lane & 15, g = lane >> 4;
  int wm = w >> 1, wn = w & 1;
  int m0 = blockIdx.y * 128, n0 = blockIdx.x * 128;
  f32x4 acc[4][4] = {};

  const char* Ab = (const char*)A;
  const char* Bb = (const char*)BT;
  for (int k0 = 0; k0 < K; k0 += 64) {
    __syncthreads();
    #pragma unroll
    for (int i = 0; i < 4; i++) {
      int chb = i * 256 + w * 64;
      int ch = chb + lane;
      int row = ch >> 3, cb = (ch & 7) ^ (row & 7);
      gload16(Ab + (((size_t)(m0 + row) * K + k0) << 1) + (cb << 4), As + chb * 16);
      gload16(Bb + (((size_t)(n0 + row) * K + k0) << 1) + (cb << 4), Bs + chb * 16);
    }
    __syncthreads();
    #pragma unroll
    for (int s = 0; s < 2; s++) {
      bf16x8 af[4], bfr[4];
      #pragma unroll
      for (int mt = 0; mt < 4; mt++) {
        int arow = wm * 64 + mt * 16 + r;
        int cb = (s * 4 + g) ^ (arow & 7);
        af[mt] = *(const bf16x8*)(As + arow * 128 + cb * 16);
      }
      #pragma unroll
      for (int nt = 0; nt < 4; nt++) {
        int brow = wn * 64 + nt * 16 + r;
        int cb = (s * 4 + g) ^ (brow & 7);
        bfr[nt] = *(const bf16x8*)(Bs + brow * 128 + cb * 16);
      }
      #pragma unroll
      for (int mt = 0; mt < 4; mt++)
        #pragma unroll
        for (int nt = 0; nt < 4; nt++)
          acc[mt][nt] = __builtin_amdgcn_mfma_f32_16x16x32_bf16(
              af[mt], bfr[nt], acc[mt][nt], 0, 0, 0);
    }
  }
  #pragma unroll
  for (int nt = 0; nt < 4; nt++) {
    int col = n0 + wn * 64 + nt * 16 + r;
    float bv = bias[col];
    bool vcols = false;
    if constexpr (FUSEV) vcols = (col >= 2048);  // uniform per nt (16-aligned bases)
    if (vcols) {
      int hd = col - 2048;
      size_t vrowbase = ((size_t)(hd >> 6)) * HD + (hd & 63);
      #pragma unroll
      for (int mt = 0; mt < 4; mt++) {
        #pragma unroll
        for (int rr = 0; rr < 4; rr++) {
          int row = m0 + wm * 64 + mt * 16 + g * 4 + rr;
          float v = acc[mt][nt][rr] + bv;
          VtOut[((size_t)(row >> 11) * NH * HD + vrowbase) * SEQ + (row & 2047)] = f2bf(v);
        }
      }
    } else {
      #pragma unroll
      for (int mt = 0; mt < 4; mt++) {
        #pragma unroll
        for (int rr = 0; rr < 4; rr++) {
          int row = m0 + wm * 64 + mt * 16 + g * 4 + rr;
          float v = acc[mt][nt][rr] + bv;
          if constexpr (sizeof(OutT) == 2) {
            C[(size_t)row * N + col] = (OutT)f2bf(v);
          } else {
            C[(size_t)row * N + col] = v;
          }
        }
      }
    }
  }
}

// ---------------- MFMA flash attention: 8 waves, dbuf K/V, defer-max ----------------
// FROZEN: byte-identical to the round-7/round-11/round-12 green kernel. Do not edit.
// grid (SEQ/128, NH, NBATCH), 512 thr = 8 waves; wave w owns q-rows [w*16, w*16+16).
// S^T = mfma(K, Q): lane owns the P-row for q = lane&15; kv = 16nt + 4g + rr.
// O^T = mfma16(V^T, P^T): B-frag k = 4g+j == lane's own kv. No P LDS round-trip.
__global__ __launch_bounds__(512, 4) void attn_mfma_kernel(
    const unsigned short* __restrict__ qkv, const unsigned short* __restrict__ Vt,
    const float* __restrict__ maskMulG, unsigned short* __restrict__ av) {
  __shared__ __align__(16) char Q_s[16384];     // [qrow 128][d 64] bf16, chunk-swizzled
  __shared__ __align__(16) char K_s[2][8192];   // dbuf [kv 64][d 64]
  __shared__ __align__(16) char V_s[2][8192];   // dbuf [d 64][kv 64] (V^T)
  int tid = threadIdx.x;
  int lane = tid & 63, w = tid >> 6;
  int r = lane & 15, g = lane >> 4;
  int qt = blockIdx.x, h = blockIdx.y, bn = blockIdx.z;
  size_t tok0 = (size_t)bn * SEQ;

  const char* qb = (const char*)qkv + (((tok0 + qt * 128) * 3072) + h * 64) * 2;
  const char* kb0 = (const char*)qkv + ((tok0 * 3072) + 1024 + h * 64) * 2;
  const char* vb0 = (const char*)Vt + (((size_t)(bn * NH + h) * HD) * SEQ) * 2;

  // Q staging: 1024 chunks over 8 waves
  #pragma unroll
  for (int i = 0; i < 2; i++) {
    int chb = i * 512 + w * 64;
    int ch = chb + lane;
    int row = ch >> 3, cb = (ch & 7) ^ (row & 7);
    gload16(qb + (size_t)row * 6144 + (cb << 4), Q_s + chb * 16);
  }
  // K/V tile staging: 512 chunks each, 1 gload per lane each
  auto stage_kv = [&](int kt, int buf) {
    int chb = w * 64;
    int ch = chb + lane;
    int row = ch >> 3, cb = (ch & 7) ^ (row & 7);
    gload16(kb0 + (size_t)(kt * 64 + row) * 6144 + (cb << 4), K_s[buf] + chb * 16);
    gload16(vb0 + (size_t)row * 4096 + (size_t)kt * 128 + (cb << 4), V_s[buf] + chb * 16);
  };
  stage_kv(0, 0);
  __syncthreads();

  float mstate = -30000.0f;
  float lstate = 0.f;
  f32x4 o_acc[4] = {};  // [dt]: d = 16*dt + 4*g + rr, q = w*16 + r

  const float CC = 0.18033688011112042f;   // 0.125 * log2(e)
  const float DEFER = 44.3614195558365f;   // 8 / CC (raw-score units)

  for (int kt = 0; kt < SEQ / 64; kt++) {
    int cur = kt & 1;
    // mask loads FIRST (so their waitcnt doesn't drain the prefetch gloads)
    float4 mmv[4];
    #pragma unroll
    for (int nt = 0; nt < 4; nt++)
      mmv[nt] = *(const float4*)(maskMulG + tok0 + kt * 64 + nt * 16 + 4 * g);
    // prefetch next K/V tile into the other buffer
    if (kt + 1 < SEQ / 64) stage_kv(kt + 1, cur ^ 1);

    // ---- S^T = K Q^T : sa[nt], row(kv) = nt*16 + 4g+rr, col(q) = r ----
    f32x4 sa[4] = {};
    #pragma unroll
    for (int s = 0; s < 2; s++) {
      int qrow = w * 16 + r;
      int cbq = (s * 4 + g) ^ (qrow & 7);
      bf16x8 qf = *(const bf16x8*)(Q_s + qrow * 128 + cbq * 16);
      #pragma unroll
      for (int nt = 0; nt < 4; nt++) {
        int krow = nt * 16 + r;
        int cb = (s * 4 + g) ^ (krow & 7);
        bf16x8 kf = *(const bf16x8*)(K_s[cur] + krow * 128 + cb * 16);
        sa[nt] = __builtin_amdgcn_mfma_f32_16x16x32_bf16(kf, qf, sa[nt], 0, 0, 0);
      }
    }

    // ---- in-register softmax (lane owns one q-row's 16 kv values) ----
    float sv[16];
    #pragma unroll
    for (int nt = 0; nt < 4; nt++)
      #pragma unroll
      for (int rr = 0; rr < 4; rr++) sv[nt * 4 + rr] = sa[nt][rr];
    // balanced max tree
    float m01 = fmaxf(sv[0], sv[1]),   m23 = fmaxf(sv[2], sv[3]);
    float m45 = fmaxf(sv[4], sv[5]),   m67 = fmaxf(sv[6], sv[7]);
    float m89 = fmaxf(sv[8], sv[9]),   mab = fmaxf(sv[10], sv[11]);
    float mcd = fmaxf(sv[12], sv[13]), mef = fmaxf(sv[14], sv[15]);
    float mx = fmaxf(fmaxf(fmaxf(m01, m23), fmaxf(m45, m67)),
                     fmaxf(fmaxf(m89, mab), fmaxf(mcd, mef)));
    mx = fmaxf(mx, __shfl_xor(mx, 16));
    mx = fmaxf(mx, __shfl_xor(mx, 32));
    // defer-max (T13): only rescale when max grew beyond threshold
    if (__any(mx > mstate + DEFER)) {
      float mnew = fmaxf(mstate, mx);
      float alpha = exp2f((mstate - mnew) * CC);  // first tile: underflows to 0
      lstate *= alpha;
      #pragma unroll
      for (int dt = 0; dt < 4; dt++) o_acc[dt] *= alpha;
      mstate = mnew;
    }
    float mc = mstate * CC;
    float p[16];
    float rs = 0.f;
    #pragma unroll
    for (int nt = 0; nt < 4; nt++) {
      float q0 = exp2f(fmaf(sv[nt * 4 + 0], CC, -mc)) * ((const float*)&mmv[nt])[0];
      float q1 = exp2f(fmaf(sv[nt * 4 + 1], CC, -mc)) * ((const float*)&mmv[nt])[1];
      float q2 = exp2f(fmaf(sv[nt * 4 + 2], CC, -mc)) * ((const float*)&mmv[nt])[2];
      float q3 = exp2f(fmaf(sv[nt * 4 + 3], CC, -mc)) * ((const float*)&mmv[nt])[3];
      p[nt * 4 + 0] = q0; p[nt * 4 + 1] = q1; p[nt * 4 + 2] = q2; p[nt * 4 + 3] = q3;
      rs += (q0 + q1) + (q2 + q3);
    }
    rs += __shfl_xor(rs, 16);
    rs += __shfl_xor(rs, 32);
    lstate += rs;

    // ---- pack P^T B-fragments (cvt_pk: 1 op / 2 values) ----
    bf16x4 bq[4];
    #pragma unroll
    for (int s4 = 0; s4 < 4; s4++) {
      uint2 u;
      u.x = cvt_pk_bf16(p[4 * s4 + 0], p[4 * s4 + 1]);
      u.y = cvt_pk_bf16(p[4 * s4 + 2], p[4 * s4 + 3]);
      bq[s4] = __builtin_bit_cast(bf16x4, u);
    }
    // ---- O^T += V^T P^T (vf loaded per-s4 to cap VGPR) ----
    #pragma unroll
    for (int s4 = 0; s4 < 4; s4++) {
      #pragma unroll
      for (int dt = 0; dt < 4; dt++) {
        int row = dt * 16 + r;
        int chunk = (2 * s4 + (g >> 1)) ^ (row & 7);
        bf16x4 vf = *(const bf16x4*)(V_s[cur] + row * 128 + chunk * 16 + (g & 1) * 8);
        o_acc[dt] = mfma16(vf, bq[s4], o_acc[dt]);
      }
    }
    __syncthreads();  // staging (next buf) done + all waves done reading cur buf
  }

  // ---- epilogue: O^T frag -> av[q][h*64 + d], d = 16dt + 4g + rr ----
  float invl = 1.0f / fmaxf(lstate, 1e-30f);
  size_t qrow = tok0 + (size_t)qt * 128 + w * 16 + r;
  unsigned short* base = av + qrow * D_MODEL + h * 64;
  #pragma unroll
  for (int dt = 0; dt < 4; dt++) {
    ushort4 o4 = {f2bf(o_acc[dt][0] * invl), f2bf(o_acc[dt][1] * invl),
                  f2bf(o_acc[dt][2] * invl), f2bf(o_acc[dt][3] * invl)};
    *(ushort4*)(base + dt * 16 + 4 * g) = o4;
  }
}

// ---------------- launch ----------------
extern "C" void kernel_launch(void* const* d_in, const int* in_sizes, int n_in,
                              void* d_out, int out_size, void* d_ws, size_t ws_size,
                              hipStream_t stream) {
  const float* x        = (const float*)d_in[0];
  const void*  mask     = d_in[1];
  const float* ln_in_w  = (const float*)d_in[2];
  const float* ln_in_b  = (const float*)d_in[3];
  const float* qkv_w    = (const float*)d_in[4];
  const float* qkv_b    = (const float*)d_in[5];
  const float* out_w    = (const float*)d_in[6];
  const float* out_b    = (const float*)d_in[7];
  const float* ln_out_w = (const float*)d_in[8];
  const float* ln_out_b = (const float*)d_in[9];
  float* out = (float*)d_out;

  const size_t MB = 1024 * 1024;
  char* ws = (char*)d_ws;
  unsigned short* xn      = (unsigned short*)(ws);             // 8 MB bf16
  unsigned short* qkv     = (unsigned short*)(ws + 8 * MB);    // 24 MB bf16 (V part unused)
  unsigned short* Vt      = (unsigned short*)(ws + 32 * MB);   // 8 MB bf16
  unsigned short* av      = (unsigned short*)(ws + 40 * MB);   // 8 MB bf16
  unsigned short* proj    = (unsigned short*)(ws + 48 * MB);   // 8 MB bf16
  unsigned short* qkv_wT  = (unsigned short*)(ws + 64 * MB);   // 6 MB bf16
  unsigned short* out_wT  = (unsigned short*)(ws + 70 * MB);   // 2 MB bf16
  float*          maskMul = (float*)(ws + 72 * MB);            // 16 KB

  // fused: mask convert (16) | weight transpose (1024) | LN1 (4096)
  pre_kernel<<<16 + 1024 + NTOK, 256, 0, stream>>>(
      mask, maskMul, qkv_w, qkv_wT, out_w, out_wT, x, ln_in_w, ln_in_b, xn);

  // QKV GEMM; V columns written transposed straight to Vt
  gemm_mfma_kernel<unsigned short, true>
      <<<dim3(3 * D_MODEL / 128, NTOK / 128), 256, 0, stream>>>(
      xn, qkv_wT, qkv_b, qkv, NTOK, 3 * D_MODEL, D_MODEL, Vt);

  attn_mfma_kernel<<<dim3(SEQ / 128, NH, NBATCH), 512, 0, stream>>>(
      qkv, Vt, maskMul, av);

  gemm_mfma_kernel<unsigned short, false>
      <<<dim3(D_MODEL / 128, NTOK / 128), 256, 0, stream>>>(
      av, out_wT, out_b, proj, NTOK, D_MODEL, D_MODEL, nullptr);

  ln2_kernel<<<NTOK, 256, 0, stream>>>(proj, ln_out_w, ln_out_b, out);
}